// Round 12
// baseline (1253.108 us; speedup 1.0000x reference)
//
#include <hip/hip_runtime.h>
#include <math.h>

// Problem constants (C, HID, etc. are structural; N and E taken from in_sizes)
#define CDIM 64
#define NBES 8

#define SQRT3_F     1.7320508075688772f
#define INV_SQRT3_F 0.57735026918962576f
#define INV_SQRT2_F 0.70710678118654752f
#define INV_AVG_NN  0.0625f

__device__ __forceinline__ float silu(float x) {
    return x / (1.0f + expf(-x));
}

// ---------------------------------------------------------------------------
// Counting sort of the edge list by SENDER. The edge kernels are
// order-agnostic (atomic accumulation), so feeding them a sender-sorted
// permutation changes only a pointer argument -- the frozen k_edge/k_edge0
// binaries are untouched. Sorted senders turn the message-phase x0/x1
// gathers (random, ~L3-latency) into L1-resident broadcasts (~4 distinct
// senders per 64-edge block at avg degree 16). Receivers remain randomly
// distributed, so the atomic contention pattern is statistically unchanged.

__global__ __launch_bounds__(256) void k_hist(const int* __restrict__ eidx,
                                              int* __restrict__ cnt, int ne) {
    int e = blockIdx.x * 256 + threadIdx.x;
    if (e < ne) atomicAdd(&cnt[eidx[e]], 1);
}

// Single-block exclusive scan over nn counters (in place).
__global__ __launch_bounds__(1024) void k_scan(int* __restrict__ cnt, int nn) {
    __shared__ int part[1024];
    const int t = threadIdx.x;
    const int chunk = (nn + 1023) / 1024;
    const int lo = t * chunk;
    const int hi = min(lo + chunk, nn);
    int sum = 0;
    for (int i = lo; i < hi; ++i) sum += cnt[i];
    part[t] = sum;
    __syncthreads();
    for (int off = 1; off < 1024; off <<= 1) {
        int v = (t >= off) ? part[t - off] : 0;
        __syncthreads();
        part[t] += v;
        __syncthreads();
    }
    int run = (t == 0) ? 0 : part[t - 1];  // exclusive base of this chunk
    for (int i = lo; i < hi; ++i) {
        int c = cnt[i];
        cnt[i] = run;
        run += c;
    }
}

__global__ __launch_bounds__(256) void k_scatter(const int* __restrict__ eidx,
                                                 int* __restrict__ cnt,
                                                 int* __restrict__ eidx2,
                                                 int ne) {
    int e = blockIdx.x * 256 + threadIdx.x;
    if (e < ne) {
        int s = eidx[e];
        int p = atomicAdd(&cnt[s], 1);
        eidx2[p] = s;
        eidx2[ne + p] = eidx[ne + e];
    }
}

// ---------------------------------------------------------------------------
// Layer-0 front end, fully fused: x0 = embed[species] @ W0 computed straight
// from the embedding table (wave-uniform row), h0/h1 zeroed as scatter
// accumulators. x1 is NOT computed (h1==0 at layer 0).
__global__ __launch_bounds__(256) void k_lin0(
    float* __restrict__ h0, float* __restrict__ h1,
    const int* __restrict__ species, const float* __restrict__ embedW,
    const float* __restrict__ W0, float* __restrict__ x0, int nnodes) {
    const int w = threadIdx.x >> 6, k = threadIdx.x & 63;
    const int n = blockIdx.x * 4 + w;
    if (n >= nnodes) return;
    const float* er = embedW + species[n] * 64;  // wave-uniform
    float a0 = 0.f;
    for (int c = 0; c < 64; ++c) a0 = fmaf(er[c], W0[c * 64 + k], a0);
    x0[n * 64 + k] = a0;
    h0[n * 64 + k] = 0.f;
    h1[n * 192 + k] = 0.f;
    h1[n * 192 + 64 + k] = 0.f;
    h1[n * 192 + 128 + k] = 0.f;
}

// ---------------------------------------------------------------------------
// LAYER-0 edge kernel. BYTE-IDENTICAL to round-10/11 (~430 us verified).
__global__ __launch_bounds__(320, 4) void k_edge0(
    const float* __restrict__ pos, const int* __restrict__ eidx,
    const float* __restrict__ x0,
    const float* __restrict__ W1, const float* __restrict__ W2,
    const float* __restrict__ W3,
    float* __restrict__ M0, float* __restrict__ M1, int nedges) {
    __shared__ __align__(16) float sFEAT[64][8];
    __shared__ float sY1[64][3];
    __shared__ int sSend[64];
    __shared__ int sRecv[64];
    __shared__ __align__(16) float sH2[64 * 68];
    __shared__ __align__(16) float sU0[4352];  // union: sH1T[64*68] | sTP[2][16][68]

    float* const sH1T = sU0;  // [k][edge], stride 68
    float* const sTP = sU0;   // [2][16][68]

    const int t = threadIdx.x;
    const int wv = t >> 6;

    // ---- P0: geometry + radial features (fp64 for accuracy), threads 0..63
    if (t < 64) {
        int e = blockIdx.x * 64 + t;
        int s = 0, r = 0;
        float y0 = 0.f, y1 = 0.f, y2 = 0.f;
        float feats[NBES];
#pragma unroll
        for (int b = 0; b < NBES; ++b) feats[b] = 0.f;
        if (e < nedges) {
            s = eidx[e];
            r = eidx[nedges + e];
            double dx = (double)pos[3 * s + 0] - (double)pos[3 * r + 0];
            double dy = (double)pos[3 * s + 1] - (double)pos[3 * r + 1];
            double dz = (double)pos[3 * s + 2] - (double)pos[3 * r + 2];
            double rr = sqrt(dx * dx + dy * dy + dz * dz);
            if (rr < 1e-6) rr = 1e-6;
            double inv = 1.0 / rr;
            y0 = (float)(1.7320508075688772 * dx * inv);
            y1 = (float)(1.7320508075688772 * dy * inv);
            y2 = (float)(1.7320508075688772 * dz * inv);
            double xx = rr * 0.2;  // r / R_MAX
            double f = 0.0;
            if (xx < 1.0) {
                double x2 = xx * xx, x3 = x2 * xx, x6 = x3 * x3;
                f = 1.0 - 28.0 * x6 + 48.0 * x6 * xx - 21.0 * x6 * x2;
            }
            double pref = 0.63245553203367587 * f * inv;  // sqrt(2/R_MAX)
#pragma unroll
            for (int b = 0; b < NBES; ++b) {
                double arg = (double)(b + 1) * 3.14159265358979324 * rr * 0.2;
                feats[b] = (float)(sin(arg) * pref);
            }
        }
        sSend[t] = s;
        sRecv[t] = r;
        sY1[t][0] = y0; sY1[t][1] = y1; sY1[t][2] = y2;
#pragma unroll
        for (int b = 0; b < NBES; ++b) sFEAT[t][b] = feats[b];
    }
    __syncthreads();

    // ---- P1: hid1 = silu(feat @ W1) -> sH1T[k][edge] (transposed, stride 68)
    if (t < 256) {
        const int j = t & 63;
        float w1c[NBES];
#pragma unroll
        for (int b = 0; b < NBES; ++b) w1c[b] = W1[b * 64 + j];
#pragma unroll
        for (int i = 0; i < 16; ++i) {
            int el = wv * 16 + i;
            const float4* fr = (const float4*)(&sFEAT[el][0]);
            float4 f0 = fr[0], f1 = fr[1];
            float acc = 0.f;
            acc = fmaf(f0.x, w1c[0], acc);
            acc = fmaf(f0.y, w1c[1], acc);
            acc = fmaf(f0.z, w1c[2], acc);
            acc = fmaf(f0.w, w1c[3], acc);
            acc = fmaf(f1.x, w1c[4], acc);
            acc = fmaf(f1.y, w1c[5], acc);
            acc = fmaf(f1.z, w1c[6], acc);
            acc = fmaf(f1.w, w1c[7], acc);
            sH1T[j * 68 + el] = silu(acc);
        }
    }
    __syncthreads();

    // ---- P2: hid2 = silu(hid1 @ W2), 4 edges x 4 cols per thread
    if (t < 256) {
        const int eg = t >> 4;
        const int j4 = (t & 15) * 4;
        float a00 = 0.f, a01 = 0.f, a02 = 0.f, a03 = 0.f;
        float a10 = 0.f, a11 = 0.f, a12 = 0.f, a13 = 0.f;
        float a20 = 0.f, a21 = 0.f, a22 = 0.f, a23 = 0.f;
        float a30 = 0.f, a31 = 0.f, a32 = 0.f, a33 = 0.f;
#pragma unroll 4
        for (int k = 0; k < 64; ++k) {
            float4 av = *(const float4*)&sH1T[k * 68 + 4 * eg];
            float4 wv4 = *(const float4*)&W2[k * 64 + j4];
            a00 = fmaf(av.x, wv4.x, a00); a01 = fmaf(av.x, wv4.y, a01);
            a02 = fmaf(av.x, wv4.z, a02); a03 = fmaf(av.x, wv4.w, a03);
            a10 = fmaf(av.y, wv4.x, a10); a11 = fmaf(av.y, wv4.y, a11);
            a12 = fmaf(av.y, wv4.z, a12); a13 = fmaf(av.y, wv4.w, a13);
            a20 = fmaf(av.z, wv4.x, a20); a21 = fmaf(av.z, wv4.y, a21);
            a22 = fmaf(av.z, wv4.z, a22); a23 = fmaf(av.z, wv4.w, a23);
            a30 = fmaf(av.w, wv4.x, a30); a31 = fmaf(av.w, wv4.y, a31);
            a32 = fmaf(av.w, wv4.z, a32); a33 = fmaf(av.w, wv4.w, a33);
        }
        *(float4*)&sH2[(4 * eg + 0) * 68 + j4] =
            make_float4(silu(a00), silu(a01), silu(a02), silu(a03));
        *(float4*)&sH2[(4 * eg + 1) * 68 + j4] =
            make_float4(silu(a10), silu(a11), silu(a12), silu(a13));
        *(float4*)&sH2[(4 * eg + 2) * 68 + j4] =
            make_float4(silu(a20), silu(a21), silu(a22), silu(a23));
        *(float4*)&sH2[(4 * eg + 3) * 68 + j4] =
            make_float4(silu(a30), silu(a31), silu(a32), silu(a33));
    }
    __syncthreads();  // sH2 ready; sH1T dead -> union free for sTP

    // ---- P3: GEMM over tpw paths 0,1 only (cols 0..127).
    const int eb16 = t & 15;
    const int cb8 = (t >> 4) * 8;  // 0..120 for t<256
    float acc[4][8];
#pragma unroll
    for (int i = 0; i < 4; ++i)
#pragma unroll
        for (int j = 0; j < 8; ++j) acc[i][j] = 0.f;

    if (t < 256) {
#pragma unroll 1
        for (int kt = 0; kt < 16; ++kt) {
            float4 h[4];
#pragma unroll
            for (int i = 0; i < 4; ++i)
                h[i] = *(const float4*)&sH2[(i * 16 + eb16) * 68 + kt * 4];
#pragma unroll
            for (int kk = 0; kk < 4; ++kk) {
                const int k = kt * 4 + kk;
                float4 wa = *(const float4*)&W3[k * 320 + cb8];
                float4 wb = *(const float4*)&W3[k * 320 + cb8 + 4];
#pragma unroll
                for (int i = 0; i < 4; ++i) {
                    float hv = (kk == 0) ? h[i].x
                             : (kk == 1) ? h[i].y
                             : (kk == 2) ? h[i].z
                                         : h[i].w;
                    acc[i][0] = fmaf(hv, wa.x, acc[i][0]);
                    acc[i][1] = fmaf(hv, wa.y, acc[i][1]);
                    acc[i][2] = fmaf(hv, wa.z, acc[i][2]);
                    acc[i][3] = fmaf(hv, wa.w, acc[i][3]);
                    acc[i][4] = fmaf(hv, wb.x, acc[i][4]);
                    acc[i][5] = fmaf(hv, wb.y, acc[i][5]);
                    acc[i][6] = fmaf(hv, wb.z, acc[i][6]);
                    acc[i][7] = fmaf(hv, wb.w, acc[i][7]);
                }
            }
        }
    }

    // ---- P4: 4 message phases, 16 edges each.
    const int p0 = cb8 >> 6;
    const int c0 = cb8 & 63;
#pragma unroll
    for (int g = 0; g < 4; ++g) {
        if (t < 256) {
            const int row = (p0 * 16 + eb16) * 68 + c0;
            *(float4*)&sTP[row] =
                make_float4(acc[g][0], acc[g][1], acc[g][2], acc[g][3]);
            *(float4*)&sTP[row + 4] =
                make_float4(acc[g][4], acc[g][5], acc[g][6], acc[g][7]);
        }
        __syncthreads();  // tpw staged
        for (int v = t; v < 1024; v += 320) {
            int i = v >> 6, cc = v & 63;
            int el = g * 16 + i;
            int s = sSend[el], r = sRecv[el];
            float X0 = x0[s * 64 + cc];
            float Yx = sY1[el][0], Yy = sY1[el][1], Yz = sY1[el][2];
            float t0 = sTP[(0 * 16 + i) * 68 + cc];
            float t1 = sTP[(1 * 16 + i) * 68 + cc];
            float m0 = t0 * X0;
            float m1 = t1 * X0 * INV_AVG_NN;
            atomicAdd(&M0[r * 64 + cc], m0 * INV_AVG_NN);
            atomicAdd(&M1[r * 192 + cc], m1 * Yx);
            atomicAdd(&M1[r * 192 + 64 + cc], m1 * Yy);
            atomicAdd(&M1[r * 192 + 128 + cc], m1 * Yz);
        }
        __syncthreads();  // sTP reads done before next phase overwrites it
    }
}

// ---------------------------------------------------------------------------
// Edge kernel: 64 edges per 320-thread block. BYTE-IDENTICAL to the round-6
// version (602 us; r9/r10/r11 confirmed binary stability across TU changes).
// Frozen: r7/r8 perturbations cost 95-240 us.
__global__ __launch_bounds__(320, 4) void k_edge(
    const float* __restrict__ pos, const int* __restrict__ eidx,
    const float* __restrict__ x0, const float* __restrict__ x1,
    const float* __restrict__ W1, const float* __restrict__ W2,
    const float* __restrict__ W3,
    float* __restrict__ M0, float* __restrict__ M1, int nedges) {
    __shared__ __align__(16) float sFEAT[64][8];
    __shared__ float sY1[64][3];
    __shared__ int sSend[64];
    __shared__ int sRecv[64];
    __shared__ __align__(16) float sH2[64 * 68];  // pad 68: b128 rows, banks spread
    __shared__ __align__(16) float sU[5440];      // union: sH1T[64*68] | sTP[5*16*68]

    float* const sH1T = sU;  // [k][edge], stride 68
    float* const sTP = sU;   // [5][16][68]

    const int t = threadIdx.x;
    const int eb = t & 7;          // GEMM: edge sub-index (edges i*8+eb)
    const int cb8 = (t >> 3) * 8;  // GEMM: first owned tpw column (0..312)
    const int wv = t >> 6;         // wave index == path index of owned cols
    const int c0 = cb8 & 63;       // channel offset within path block

    // ---- P0: geometry + radial features (fp64 for accuracy), threads 0..63
    if (t < 64) {
        int e = blockIdx.x * 64 + t;
        int s = 0, r = 0;
        float y0 = 0.f, y1 = 0.f, y2 = 0.f;
        float feats[NBES];
#pragma unroll
        for (int b = 0; b < NBES; ++b) feats[b] = 0.f;
        if (e < nedges) {
            s = eidx[e];
            r = eidx[nedges + e];
            double dx = (double)pos[3 * s + 0] - (double)pos[3 * r + 0];
            double dy = (double)pos[3 * s + 1] - (double)pos[3 * r + 1];
            double dz = (double)pos[3 * s + 2] - (double)pos[3 * r + 2];
            double rr = sqrt(dx * dx + dy * dy + dz * dz);
            if (rr < 1e-6) rr = 1e-6;
            double inv = 1.0 / rr;
            y0 = (float)(1.7320508075688772 * dx * inv);
            y1 = (float)(1.7320508075688772 * dy * inv);
            y2 = (float)(1.7320508075688772 * dz * inv);
            double xx = rr * 0.2;  // r / R_MAX
            double f = 0.0;
            if (xx < 1.0) {
                double x2 = xx * xx, x3 = x2 * xx, x6 = x3 * x3;
                f = 1.0 - 28.0 * x6 + 48.0 * x6 * xx - 21.0 * x6 * x2;
            }
            double pref = 0.63245553203367587 * f * inv;  // sqrt(2/R_MAX)
#pragma unroll
            for (int b = 0; b < NBES; ++b) {
                double arg = (double)(b + 1) * 3.14159265358979324 * rr * 0.2;
                feats[b] = (float)(sin(arg) * pref);
            }
        }
        sSend[t] = s;
        sRecv[t] = r;
        sY1[t][0] = y0; sY1[t][1] = y1; sY1[t][2] = y2;
#pragma unroll
        for (int b = 0; b < NBES; ++b) sFEAT[t][b] = feats[b];
    }
    __syncthreads();

    // ---- P1: hid1 = silu(feat @ W1) -> sH1T[k][edge] (transposed, stride 68)
    if (t < 256) {
        const int j = t & 63;
        float w1c[NBES];
#pragma unroll
        for (int b = 0; b < NBES; ++b) w1c[b] = W1[b * 64 + j];
#pragma unroll
        for (int i = 0; i < 16; ++i) {
            int el = wv * 16 + i;
            const float4* fr = (const float4*)(&sFEAT[el][0]);  // broadcast reads
            float4 f0 = fr[0], f1 = fr[1];
            float acc = 0.f;
            acc = fmaf(f0.x, w1c[0], acc);
            acc = fmaf(f0.y, w1c[1], acc);
            acc = fmaf(f0.z, w1c[2], acc);
            acc = fmaf(f0.w, w1c[3], acc);
            acc = fmaf(f1.x, w1c[4], acc);
            acc = fmaf(f1.y, w1c[5], acc);
            acc = fmaf(f1.z, w1c[6], acc);
            acc = fmaf(f1.w, w1c[7], acc);
            sH1T[j * 68 + el] = silu(acc);
        }
    }
    __syncthreads();

    // ---- P2: hid2 = silu(hid1 @ W2), 4 edges x 4 cols per thread,
    // A from sH1T (b128), B from global W2 (L1-resident, 16KB).
    if (t < 256) {
        const int eg = t >> 4;         // edge group: edges 4*eg..+4
        const int j4 = (t & 15) * 4;   // col group: cols j4..j4+4
        float a00 = 0.f, a01 = 0.f, a02 = 0.f, a03 = 0.f;
        float a10 = 0.f, a11 = 0.f, a12 = 0.f, a13 = 0.f;
        float a20 = 0.f, a21 = 0.f, a22 = 0.f, a23 = 0.f;
        float a30 = 0.f, a31 = 0.f, a32 = 0.f, a33 = 0.f;
#pragma unroll 4
        for (int k = 0; k < 64; ++k) {
            float4 av = *(const float4*)&sH1T[k * 68 + 4 * eg];
            float4 wv4 = *(const float4*)&W2[k * 64 + j4];
            a00 = fmaf(av.x, wv4.x, a00); a01 = fmaf(av.x, wv4.y, a01);
            a02 = fmaf(av.x, wv4.z, a02); a03 = fmaf(av.x, wv4.w, a03);
            a10 = fmaf(av.y, wv4.x, a10); a11 = fmaf(av.y, wv4.y, a11);
            a12 = fmaf(av.y, wv4.z, a12); a13 = fmaf(av.y, wv4.w, a13);
            a20 = fmaf(av.z, wv4.x, a20); a21 = fmaf(av.z, wv4.y, a21);
            a22 = fmaf(av.z, wv4.z, a22); a23 = fmaf(av.z, wv4.w, a23);
            a30 = fmaf(av.w, wv4.x, a30); a31 = fmaf(av.w, wv4.y, a31);
            a32 = fmaf(av.w, wv4.z, a32); a33 = fmaf(av.w, wv4.w, a33);
        }
        *(float4*)&sH2[(4 * eg + 0) * 68 + j4] =
            make_float4(silu(a00), silu(a01), silu(a02), silu(a03));
        *(float4*)&sH2[(4 * eg + 1) * 68 + j4] =
            make_float4(silu(a10), silu(a11), silu(a12), silu(a13));
        *(float4*)&sH2[(4 * eg + 2) * 68 + j4] =
            make_float4(silu(a20), silu(a21), silu(a22), silu(a23));
        *(float4*)&sH2[(4 * eg + 3) * 68 + j4] =
            make_float4(silu(a30), silu(a31), silu(a32), silu(a33));
    }
    __syncthreads();  // sH2 ready; sH1T dead -> union free for sTP

    // ---- P3: barrier-free GEMM
    // acc[i][j] = sum_k sH2[i*8+eb][k] * W3[k][cb8+j]; W3 via VMEM (L2-hot)
    float acc[8][8];
#pragma unroll
    for (int i = 0; i < 8; ++i)
#pragma unroll
        for (int j = 0; j < 8; ++j) acc[i][j] = 0.f;

#pragma unroll 1
    for (int kt = 0; kt < 16; ++kt) {  // K-step 4
        float4 h[8];
#pragma unroll
        for (int i = 0; i < 8; ++i)
            h[i] = *(const float4*)&sH2[(i * 8 + eb) * 68 + kt * 4];
#pragma unroll
        for (int kk = 0; kk < 4; ++kk) {
            const int k = kt * 4 + kk;
            float4 wa = *(const float4*)&W3[k * 320 + cb8];
            float4 wb = *(const float4*)&W3[k * 320 + cb8 + 4];
#pragma unroll
            for (int i = 0; i < 8; ++i) {
                float hv = (kk == 0) ? h[i].x
                         : (kk == 1) ? h[i].y
                         : (kk == 2) ? h[i].z
                                     : h[i].w;
                acc[i][0] = fmaf(hv, wa.x, acc[i][0]);
                acc[i][1] = fmaf(hv, wa.y, acc[i][1]);
                acc[i][2] = fmaf(hv, wa.z, acc[i][2]);
                acc[i][3] = fmaf(hv, wa.w, acc[i][3]);
                acc[i][4] = fmaf(hv, wb.x, acc[i][4]);
                acc[i][5] = fmaf(hv, wb.y, acc[i][5]);
                acc[i][6] = fmaf(hv, wb.z, acc[i][6]);
                acc[i][7] = fmaf(hv, wb.w, acc[i][7]);
            }
        }
    }

    // ---- P4: 4 message phases, 16 edges each. Thread stages acc[2g][*]
    // (edge g*16+eb) and acc[2g+1][*] (edge g*16+8+eb) into sTP[p][el][ch].
#pragma unroll
    for (int g = 0; g < 4; ++g) {
        {
            const int rowA = (wv * 16 + eb) * 68 + c0;
            const int rowB = (wv * 16 + 8 + eb) * 68 + c0;
            *(float4*)&sTP[rowA] =
                make_float4(acc[2 * g][0], acc[2 * g][1], acc[2 * g][2], acc[2 * g][3]);
            *(float4*)&sTP[rowA + 4] =
                make_float4(acc[2 * g][4], acc[2 * g][5], acc[2 * g][6], acc[2 * g][7]);
            *(float4*)&sTP[rowB] =
                make_float4(acc[2 * g + 1][0], acc[2 * g + 1][1], acc[2 * g + 1][2], acc[2 * g + 1][3]);
            *(float4*)&sTP[rowB + 4] =
                make_float4(acc[2 * g + 1][4], acc[2 * g + 1][5], acc[2 * g + 1][6], acc[2 * g + 1][7]);
        }
        __syncthreads();  // tpw staged
        // 16 edges x 64 channels = 1024 items over 320 threads
        for (int v = t; v < 1024; v += 320) {
            int i = v >> 6, cc = v & 63;
            int el = g * 16 + i;
            int s = sSend[el], r = sRecv[el];
            float X0 = x0[s * 64 + cc];
            float Xx = x1[s * 192 + cc];
            float Xy = x1[s * 192 + 64 + cc];
            float Xz = x1[s * 192 + 128 + cc];
            float Yx = sY1[el][0], Yy = sY1[el][1], Yz = sY1[el][2];
            float t0 = sTP[(0 * 16 + i) * 68 + cc];
            float t1 = sTP[(1 * 16 + i) * 68 + cc];
            float t2 = sTP[(2 * 16 + i) * 68 + cc];
            float t3 = sTP[(3 * 16 + i) * 68 + cc];
            float t4 = sTP[(4 * 16 + i) * 68 + cc];
            float dotp = Xx * Yx + Xy * Yy + Xz * Yz;
            float m0 = t0 * X0 + t3 * (dotp * INV_SQRT3_F);
            float cx = Xy * Yz - Xz * Yy;
            float cy = Xz * Yx - Xx * Yz;
            float cz = Xx * Yy - Xy * Yx;
            float m1x = t1 * X0 * Yx + t2 * Xx + t4 * (cx * INV_SQRT2_F);
            float m1y = t1 * X0 * Yy + t2 * Xy + t4 * (cy * INV_SQRT2_F);
            float m1z = t1 * X0 * Yz + t2 * Xz + t4 * (cz * INV_SQRT2_F);
            atomicAdd(&M0[r * 64 + cc], m0 * INV_AVG_NN);
            atomicAdd(&M1[r * 192 + cc], m1x * INV_AVG_NN);
            atomicAdd(&M1[r * 192 + 64 + cc], m1y * INV_AVG_NN);
            atomicAdd(&M1[r * 192 + 128 + cc], m1z * INV_AVG_NN);
        }
        __syncthreads();  // sTP reads done before next phase overwrites it
    }
}

// ---------------------------------------------------------------------------
// Fused layer-0 node update + layer-1 lin_up. (unchanged from round 11)
__global__ __launch_bounds__(256) void k_nodelin(
    float* __restrict__ h0, float* __restrict__ h1,
    const int* __restrict__ species,
    const float* __restrict__ linW0, const float* __restrict__ linW1,
    const float* __restrict__ prodW0, const float* __restrict__ prodW1,
    const float* __restrict__ plinW0, const float* __restrict__ plinW1,
    const float* __restrict__ lupW0, const float* __restrict__ lupW1,
    float* __restrict__ x0, float* __restrict__ x1, int nnodes) {
    __shared__ float sh[4][4][64];
    const int w = threadIdx.x >> 6, k = threadIdx.x & 63;
    const int n = blockIdx.x * 4 + w;
    const bool valid = n < nnodes;
    float v0 = valid ? h0[n * 64 + k] : 0.f;
    float v1 = valid ? h1[n * 192 + k] : 0.f;
    float v2 = valid ? h1[n * 192 + 64 + k] : 0.f;
    float v3 = valid ? h1[n * 192 + 128 + k] : 0.f;
    sh[w][0][k] = v0; sh[w][1][k] = v1; sh[w][2][k] = v2; sh[w][3][k] = v3;
    if (valid) {  // zero scatter accumulators for layer 1
        h0[n * 64 + k] = 0.f;
        h1[n * 192 + k] = 0.f;
        h1[n * 192 + 64 + k] = 0.f;
        h1[n * 192 + 128 + k] = 0.f;
    }
    __syncthreads();
    float a0 = 0.f, a1 = 0.f, a2 = 0.f, a3 = 0.f;
    for (int c = 0; c < 64; ++c) {
        float w0 = linW0[c * 64 + k], w1 = linW1[c * 64 + k];
        a0 = fmaf(sh[w][0][c], w0, a0);
        a1 = fmaf(sh[w][1][c], w1, a1);
        a2 = fmaf(sh[w][2][c], w1, a2);
        a3 = fmaf(sh[w][3][c], w1, a3);
    }
    int sp = valid ? species[n] : 0;
    float p00 = prodW0[sp * 192 + k];
    float p01 = prodW0[sp * 192 + 64 + k];
    float p02 = prodW0[sp * 192 + 128 + k];
    float p10 = prodW1[sp * 128 + k];
    float p11 = prodW1[sp * 128 + 64 + k];
    float nsq = a1 * a1 + a2 * a2 + a3 * a3;
    float b0 = p00 * a0 + p01 * (a0 * a0) + p02 * (nsq * INV_SQRT3_F);
    float b1x = p10 * a1 + p11 * (a0 * a1);
    float b1y = p10 * a2 + p11 * (a0 * a2);
    float b1z = p10 * a3 + p11 * (a0 * a3);
    __syncthreads();
    sh[w][0][k] = b0; sh[w][1][k] = b1x; sh[w][2][k] = b1y; sh[w][3][k] = b1z;
    __syncthreads();
    a0 = a1 = a2 = a3 = 0.f;
    for (int c = 0; c < 64; ++c) {
        float w0 = plinW0[c * 64 + k], w1 = plinW1[c * 64 + k];
        a0 = fmaf(sh[w][0][c], w0, a0);
        a1 = fmaf(sh[w][1][c], w1, a1);
        a2 = fmaf(sh[w][2][c], w1, a2);
        a3 = fmaf(sh[w][3][c], w1, a3);
    }
    __syncthreads();
    sh[w][0][k] = a0; sh[w][1][k] = a1; sh[w][2][k] = a2; sh[w][3][k] = a3;
    __syncthreads();
    a0 = a1 = a2 = a3 = 0.f;
    for (int c = 0; c < 64; ++c) {
        float w0 = lupW0[c * 64 + k], w1 = lupW1[c * 64 + k];
        a0 = fmaf(sh[w][0][c], w0, a0);
        a1 = fmaf(sh[w][1][c], w1, a1);
        a2 = fmaf(sh[w][2][c], w1, a2);
        a3 = fmaf(sh[w][3][c], w1, a3);
    }
    if (valid) {
        x0[n * 64 + k] = a0;
        x1[n * 192 + k] = a1;
        x1[n * 192 + 64 + k] = a2;
        x1[n * 192 + 128 + k] = a3;
    }
}

// ---------------------------------------------------------------------------
// Fused layer-1 node update + output write. (unchanged from round 11)
__global__ __launch_bounds__(256) void k_nodeout(
    const float* __restrict__ h0, const float* __restrict__ h1,
    const int* __restrict__ species,
    const float* __restrict__ linW0, const float* __restrict__ linW1,
    const float* __restrict__ prodW0, const float* __restrict__ prodW1,
    const float* __restrict__ plinW0, const float* __restrict__ plinW1,
    float4* __restrict__ out, int nnodes) {
    __shared__ float sh[4][4][64];
    const int w = threadIdx.x >> 6, k = threadIdx.x & 63;
    const int n = blockIdx.x * 4 + w;
    const bool valid = n < nnodes;
    float v0 = valid ? h0[n * 64 + k] : 0.f;
    float v1 = valid ? h1[n * 192 + k] : 0.f;
    float v2 = valid ? h1[n * 192 + 64 + k] : 0.f;
    float v3 = valid ? h1[n * 192 + 128 + k] : 0.f;
    sh[w][0][k] = v0; sh[w][1][k] = v1; sh[w][2][k] = v2; sh[w][3][k] = v3;
    __syncthreads();
    float a0 = 0.f, a1 = 0.f, a2 = 0.f, a3 = 0.f;
    for (int c = 0; c < 64; ++c) {
        float w0 = linW0[c * 64 + k], w1 = linW1[c * 64 + k];
        a0 = fmaf(sh[w][0][c], w0, a0);
        a1 = fmaf(sh[w][1][c], w1, a1);
        a2 = fmaf(sh[w][2][c], w1, a2);
        a3 = fmaf(sh[w][3][c], w1, a3);
    }
    int sp = valid ? species[n] : 0;
    float p00 = prodW0[sp * 192 + k];
    float p01 = prodW0[sp * 192 + 64 + k];
    float p02 = prodW0[sp * 192 + 128 + k];
    float p10 = prodW1[sp * 128 + k];
    float p11 = prodW1[sp * 128 + 64 + k];
    float nsq = a1 * a1 + a2 * a2 + a3 * a3;
    float b0 = p00 * a0 + p01 * (a0 * a0) + p02 * (nsq * INV_SQRT3_F);
    float b1x = p10 * a1 + p11 * (a0 * a1);
    float b1y = p10 * a2 + p11 * (a0 * a2);
    float b1z = p10 * a3 + p11 * (a0 * a3);
    __syncthreads();
    sh[w][0][k] = b0; sh[w][1][k] = b1x; sh[w][2][k] = b1y; sh[w][3][k] = b1z;
    __syncthreads();
    a0 = a1 = a2 = a3 = 0.f;
    for (int c = 0; c < 64; ++c) {
        float w0 = plinW0[c * 64 + k], w1 = plinW1[c * 64 + k];
        a0 = fmaf(sh[w][0][c], w0, a0);
        a1 = fmaf(sh[w][1][c], w1, a1);
        a2 = fmaf(sh[w][2][c], w1, a2);
        a3 = fmaf(sh[w][3][c], w1, a3);
    }
    if (valid) out[n * 64 + k] = make_float4(a0, a1, a2, a3);
}

// ---------------------------------------------------------------------------
extern "C" void kernel_launch(void* const* d_in, const int* in_sizes, int n_in,
                              void* d_out, int out_size, void* d_ws,
                              size_t ws_size, hipStream_t stream) {
    const float* positions = (const float*)d_in[0];
    const int* species = (const int*)d_in[1];
    const int* eidx = (const int*)d_in[2];
    const float* embedW = (const float*)d_in[3];
    const float* linupW0 = (const float*)d_in[4];
    const float* linupW1 = (const float*)d_in[5];
    const float* mlpW1 = (const float*)d_in[6];
    const float* mlpW2 = (const float*)d_in[7];
    const float* mlpW3 = (const float*)d_in[8];
    const float* linW0 = (const float*)d_in[9];
    const float* linW1 = (const float*)d_in[10];
    const float* prodW0 = (const float*)d_in[11];
    const float* prodW1 = (const float*)d_in[12];
    const float* plinW0 = (const float*)d_in[13];
    const float* plinW1 = (const float*)d_in[14];

    const int nn = in_sizes[0] / 3;   // 25000
    const int ne = in_sizes[2] / 2;   // 400000

    // workspace layout (floats): h0 | h1 | x0 | x1 | eidx2(int)
    float* h0 = (float*)d_ws;
    float* h1 = h0 + (size_t)nn * 64;
    float* x0 = h1 + (size_t)nn * 192;
    float* x1 = x0 + (size_t)nn * 64;
    int* eidx2 = (int*)(x1 + (size_t)nn * 192);

    const int gridNode = (nn + 3) / 4;
    const int gridEdge = (ne + 63) / 64;
    const int gridE256 = (ne + 255) / 256;

    // ---- sender-sort the edge list (pointer-swap only; frozen edge-kernel
    // binaries untouched). cnt aliases x1 (dead until k_nodelin). Guard on
    // workspace capacity; fall back to unsorted edges if tight.
    const size_t needed =
        ((size_t)nn * 512) * sizeof(float) + (size_t)2 * ne * sizeof(int);
    const int* eidx_use = eidx;
    if (ws_size >= needed) {
        int* cnt = (int*)x1;
        hipMemsetAsync(cnt, 0, (size_t)nn * sizeof(int), stream);
        k_hist<<<gridE256, 256, 0, stream>>>(eidx, cnt, ne);
        k_scan<<<1, 1024, 0, stream>>>(cnt, nn);
        k_scatter<<<gridE256, 256, 0, stream>>>(eidx, cnt, eidx2, ne);
        eidx_use = eidx2;
    }

    // ---- layer 0
    k_lin0<<<gridNode, 256, 0, stream>>>(
        h0, h1, species, embedW, linupW0, x0, nn);
    k_edge0<<<gridEdge, 320, 0, stream>>>(
        positions, eidx_use, x0, mlpW1, mlpW2, mlpW3, h0, h1, ne);

    // ---- layer-0 node update fused with layer-1 lin_up
    k_nodelin<<<gridNode, 256, 0, stream>>>(
        h0, h1, species, linW0, linW1, prodW0, prodW1, plinW0, plinW1,
        linupW0 + 4096, linupW1 + 4096, x0, x1, nn);

    // ---- layer 1: frozen general edge kernel
    k_edge<<<gridEdge, 320, 0, stream>>>(
        positions, eidx_use, x0, x1, mlpW1 + 512, mlpW2 + 4096,
        mlpW3 + 20480, h0, h1, ne);

    // ---- layer-1 node update fused with output write
    k_nodeout<<<gridNode, 256, 0, stream>>>(
        h0, h1, species, linW0 + 4096, linW1 + 4096,
        prodW0 + 768, prodW1 + 512, plinW0 + 4096, plinW1 + 4096,
        (float4*)d_out, nn);
}

// Round 13
// 1132.860 us; speedup vs baseline: 1.1061x; 1.1061x over previous
//
#include <hip/hip_runtime.h>
#include <math.h>

// Problem constants (C, HID, etc. are structural; N and E taken from in_sizes)
#define CDIM 64
#define NBES 8

#define SQRT3_F     1.7320508075688772f
#define INV_SQRT3_F 0.57735026918962576f
#define INV_SQRT2_F 0.70710678118654752f
#define INV_AVG_NN  0.0625f

__device__ __forceinline__ float silu(float x) {
    return x / (1.0f + expf(-x));
}

// ---------------------------------------------------------------------------
// Counting sort of the edge list by RECEIVER. r12 proved the gather side is
// fully latency-hidden (sender-sort removed 160MB of FETCH with zero timing
// change), so sort order is free for gathers; receiver-sorting instead makes
// same-receiver edges contiguous, enabling in-register atomic MERGING in the
// message phase (~3.2x fewer atomics). Tested on k_edge0 only this round;
// the frozen k_edge keeps the ORIGINAL unsorted eidx (pointer choice proven
// irrelevant to its timing in r12).

__global__ __launch_bounds__(256) void k_hist(const int* __restrict__ eidx,
                                              int* __restrict__ cnt, int ne) {
    int e = blockIdx.x * 256 + threadIdx.x;
    if (e < ne) atomicAdd(&cnt[eidx[ne + e]], 1);
}

// Single-block exclusive scan over nn counters (in place).
__global__ __launch_bounds__(1024) void k_scan(int* __restrict__ cnt, int nn) {
    __shared__ int part[1024];
    const int t = threadIdx.x;
    const int chunk = (nn + 1023) / 1024;
    const int lo = t * chunk;
    const int hi = min(lo + chunk, nn);
    int sum = 0;
    for (int i = lo; i < hi; ++i) sum += cnt[i];
    part[t] = sum;
    __syncthreads();
    for (int off = 1; off < 1024; off <<= 1) {
        int v = (t >= off) ? part[t - off] : 0;
        __syncthreads();
        part[t] += v;
        __syncthreads();
    }
    int run = (t == 0) ? 0 : part[t - 1];  // exclusive base of this chunk
    for (int i = lo; i < hi; ++i) {
        int c = cnt[i];
        cnt[i] = run;
        run += c;
    }
}

__global__ __launch_bounds__(256) void k_scatter(const int* __restrict__ eidx,
                                                 int* __restrict__ cnt,
                                                 int* __restrict__ eidx2,
                                                 int ne) {
    int e = blockIdx.x * 256 + threadIdx.x;
    if (e < ne) {
        int r = eidx[ne + e];
        int p = atomicAdd(&cnt[r], 1);
        eidx2[p] = eidx[e];   // sender
        eidx2[ne + p] = r;    // receiver (sort key)
    }
}

// ---------------------------------------------------------------------------
// Layer-0 front end, fully fused: x0 = embed[species] @ W0 computed straight
// from the embedding table (wave-uniform row), h0/h1 zeroed as scatter
// accumulators. x1 is NOT computed (h1==0 at layer 0).
__global__ __launch_bounds__(256) void k_lin0(
    float* __restrict__ h0, float* __restrict__ h1,
    const int* __restrict__ species, const float* __restrict__ embedW,
    const float* __restrict__ W0, float* __restrict__ x0, int nnodes) {
    const int w = threadIdx.x >> 6, k = threadIdx.x & 63;
    const int n = blockIdx.x * 4 + w;
    if (n >= nnodes) return;
    const float* er = embedW + species[n] * 64;  // wave-uniform
    float a0 = 0.f;
    for (int c = 0; c < 64; ++c) a0 = fmaf(er[c], W0[c * 64 + k], a0);
    x0[n * 64 + k] = a0;
    h0[n * 64 + k] = 0.f;
    h1[n * 192 + k] = 0.f;
    h1[n * 192 + 64 + k] = 0.f;
    h1[n * 192 + 128 + k] = 0.f;
}

// ---------------------------------------------------------------------------
// LAYER-0 edge kernel, now consuming RECEIVER-SORTED edges. P0-P3 identical
// to the verified round-10/11 version; P4 rewritten to merge same-receiver
// runs in registers: thread (q = t>>6, cc = t&63) walks its 4 contiguous
// edges of the phase, accumulating (m0, m1*Y) while the receiver repeats,
// flushing 4 atomics only on receiver change (~3.2x fewer atomics).
// Branch is wave-uniform (one wave = one q, all cc share edge indices).
__global__ __launch_bounds__(320, 4) void k_edge0(
    const float* __restrict__ pos, const int* __restrict__ eidx,
    const float* __restrict__ x0,
    const float* __restrict__ W1, const float* __restrict__ W2,
    const float* __restrict__ W3,
    float* __restrict__ M0, float* __restrict__ M1, int nedges) {
    __shared__ __align__(16) float sFEAT[64][8];
    __shared__ float sY1[64][3];
    __shared__ int sSend[64];
    __shared__ int sRecv[64];
    __shared__ __align__(16) float sH2[64 * 68];
    __shared__ __align__(16) float sU0[4352];  // union: sH1T[64*68] | sTP[2][16][68]

    float* const sH1T = sU0;  // [k][edge], stride 68
    float* const sTP = sU0;   // [2][16][68]

    const int t = threadIdx.x;
    const int wv = t >> 6;

    // ---- P0: geometry + radial features (fp64 for accuracy), threads 0..63
    if (t < 64) {
        int e = blockIdx.x * 64 + t;
        int s = 0, r = 0;
        float y0 = 0.f, y1 = 0.f, y2 = 0.f;
        float feats[NBES];
#pragma unroll
        for (int b = 0; b < NBES; ++b) feats[b] = 0.f;
        if (e < nedges) {
            s = eidx[e];
            r = eidx[nedges + e];
            double dx = (double)pos[3 * s + 0] - (double)pos[3 * r + 0];
            double dy = (double)pos[3 * s + 1] - (double)pos[3 * r + 1];
            double dz = (double)pos[3 * s + 2] - (double)pos[3 * r + 2];
            double rr = sqrt(dx * dx + dy * dy + dz * dz);
            if (rr < 1e-6) rr = 1e-6;
            double inv = 1.0 / rr;
            y0 = (float)(1.7320508075688772 * dx * inv);
            y1 = (float)(1.7320508075688772 * dy * inv);
            y2 = (float)(1.7320508075688772 * dz * inv);
            double xx = rr * 0.2;  // r / R_MAX
            double f = 0.0;
            if (xx < 1.0) {
                double x2 = xx * xx, x3 = x2 * xx, x6 = x3 * x3;
                f = 1.0 - 28.0 * x6 + 48.0 * x6 * xx - 21.0 * x6 * x2;
            }
            double pref = 0.63245553203367587 * f * inv;  // sqrt(2/R_MAX)
#pragma unroll
            for (int b = 0; b < NBES; ++b) {
                double arg = (double)(b + 1) * 3.14159265358979324 * rr * 0.2;
                feats[b] = (float)(sin(arg) * pref);
            }
        }
        sSend[t] = s;
        sRecv[t] = r;
        sY1[t][0] = y0; sY1[t][1] = y1; sY1[t][2] = y2;
#pragma unroll
        for (int b = 0; b < NBES; ++b) sFEAT[t][b] = feats[b];
    }
    __syncthreads();

    // ---- P1: hid1 = silu(feat @ W1) -> sH1T[k][edge] (transposed, stride 68)
    if (t < 256) {
        const int j = t & 63;
        float w1c[NBES];
#pragma unroll
        for (int b = 0; b < NBES; ++b) w1c[b] = W1[b * 64 + j];
#pragma unroll
        for (int i = 0; i < 16; ++i) {
            int el = wv * 16 + i;
            const float4* fr = (const float4*)(&sFEAT[el][0]);
            float4 f0 = fr[0], f1 = fr[1];
            float acc = 0.f;
            acc = fmaf(f0.x, w1c[0], acc);
            acc = fmaf(f0.y, w1c[1], acc);
            acc = fmaf(f0.z, w1c[2], acc);
            acc = fmaf(f0.w, w1c[3], acc);
            acc = fmaf(f1.x, w1c[4], acc);
            acc = fmaf(f1.y, w1c[5], acc);
            acc = fmaf(f1.z, w1c[6], acc);
            acc = fmaf(f1.w, w1c[7], acc);
            sH1T[j * 68 + el] = silu(acc);
        }
    }
    __syncthreads();

    // ---- P2: hid2 = silu(hid1 @ W2), 4 edges x 4 cols per thread
    if (t < 256) {
        const int eg = t >> 4;
        const int j4 = (t & 15) * 4;
        float a00 = 0.f, a01 = 0.f, a02 = 0.f, a03 = 0.f;
        float a10 = 0.f, a11 = 0.f, a12 = 0.f, a13 = 0.f;
        float a20 = 0.f, a21 = 0.f, a22 = 0.f, a23 = 0.f;
        float a30 = 0.f, a31 = 0.f, a32 = 0.f, a33 = 0.f;
#pragma unroll 4
        for (int k = 0; k < 64; ++k) {
            float4 av = *(const float4*)&sH1T[k * 68 + 4 * eg];
            float4 wv4 = *(const float4*)&W2[k * 64 + j4];
            a00 = fmaf(av.x, wv4.x, a00); a01 = fmaf(av.x, wv4.y, a01);
            a02 = fmaf(av.x, wv4.z, a02); a03 = fmaf(av.x, wv4.w, a03);
            a10 = fmaf(av.y, wv4.x, a10); a11 = fmaf(av.y, wv4.y, a11);
            a12 = fmaf(av.y, wv4.z, a12); a13 = fmaf(av.y, wv4.w, a13);
            a20 = fmaf(av.z, wv4.x, a20); a21 = fmaf(av.z, wv4.y, a21);
            a22 = fmaf(av.z, wv4.z, a22); a23 = fmaf(av.z, wv4.w, a23);
            a30 = fmaf(av.w, wv4.x, a30); a31 = fmaf(av.w, wv4.y, a31);
            a32 = fmaf(av.w, wv4.z, a32); a33 = fmaf(av.w, wv4.w, a33);
        }
        *(float4*)&sH2[(4 * eg + 0) * 68 + j4] =
            make_float4(silu(a00), silu(a01), silu(a02), silu(a03));
        *(float4*)&sH2[(4 * eg + 1) * 68 + j4] =
            make_float4(silu(a10), silu(a11), silu(a12), silu(a13));
        *(float4*)&sH2[(4 * eg + 2) * 68 + j4] =
            make_float4(silu(a20), silu(a21), silu(a22), silu(a23));
        *(float4*)&sH2[(4 * eg + 3) * 68 + j4] =
            make_float4(silu(a30), silu(a31), silu(a32), silu(a33));
    }
    __syncthreads();  // sH2 ready; sH1T dead -> union free for sTP

    // ---- P3: GEMM over tpw paths 0,1 only (cols 0..127).
    const int eb16 = t & 15;
    const int cb8 = (t >> 4) * 8;  // 0..120 for t<256
    float acc[4][8];
#pragma unroll
    for (int i = 0; i < 4; ++i)
#pragma unroll
        for (int j = 0; j < 8; ++j) acc[i][j] = 0.f;

    if (t < 256) {
#pragma unroll 1
        for (int kt = 0; kt < 16; ++kt) {
            float4 h[4];
#pragma unroll
            for (int i = 0; i < 4; ++i)
                h[i] = *(const float4*)&sH2[(i * 16 + eb16) * 68 + kt * 4];
#pragma unroll
            for (int kk = 0; kk < 4; ++kk) {
                const int k = kt * 4 + kk;
                float4 wa = *(const float4*)&W3[k * 320 + cb8];
                float4 wb = *(const float4*)&W3[k * 320 + cb8 + 4];
#pragma unroll
                for (int i = 0; i < 4; ++i) {
                    float hv = (kk == 0) ? h[i].x
                             : (kk == 1) ? h[i].y
                             : (kk == 2) ? h[i].z
                                         : h[i].w;
                    acc[i][0] = fmaf(hv, wa.x, acc[i][0]);
                    acc[i][1] = fmaf(hv, wa.y, acc[i][1]);
                    acc[i][2] = fmaf(hv, wa.z, acc[i][2]);
                    acc[i][3] = fmaf(hv, wa.w, acc[i][3]);
                    acc[i][4] = fmaf(hv, wb.x, acc[i][4]);
                    acc[i][5] = fmaf(hv, wb.y, acc[i][5]);
                    acc[i][6] = fmaf(hv, wb.z, acc[i][6]);
                    acc[i][7] = fmaf(hv, wb.w, acc[i][7]);
                }
            }
        }
    }

    // ---- P4: 4 message phases, 16 contiguous receiver-sorted edges each.
    // Thread (q, cc) walks edges q*4..q*4+3 of the phase, merging
    // same-receiver runs; flushes only on receiver change (and at end).
    const int p0 = cb8 >> 6;
    const int c0 = cb8 & 63;
#pragma unroll
    for (int g = 0; g < 4; ++g) {
        if (t < 256) {
            const int row = (p0 * 16 + eb16) * 68 + c0;
            *(float4*)&sTP[row] =
                make_float4(acc[g][0], acc[g][1], acc[g][2], acc[g][3]);
            *(float4*)&sTP[row + 4] =
                make_float4(acc[g][4], acc[g][5], acc[g][6], acc[g][7]);
        }
        __syncthreads();  // tpw staged
        if (t < 256) {
            const int q = t >> 6, cc = t & 63;
            int r_cur = -1;
            float a0 = 0.f, ax = 0.f, ay = 0.f, az = 0.f;
#pragma unroll
            for (int j = 0; j < 4; ++j) {
                int i = q * 4 + j;
                int el = g * 16 + i;
                int s = sSend[el], r = sRecv[el];
                if (r != r_cur) {  // wave-uniform branch (one wave = one q)
                    if (r_cur >= 0) {
                        atomicAdd(&M0[r_cur * 64 + cc], a0);
                        atomicAdd(&M1[r_cur * 192 + cc], ax);
                        atomicAdd(&M1[r_cur * 192 + 64 + cc], ay);
                        atomicAdd(&M1[r_cur * 192 + 128 + cc], az);
                    }
                    r_cur = r;
                    a0 = ax = ay = az = 0.f;
                }
                float X0 = x0[s * 64 + cc];
                float t0v = sTP[(0 * 16 + i) * 68 + cc];
                float t1v = sTP[(1 * 16 + i) * 68 + cc];
                float m0 = t0v * X0 * INV_AVG_NN;
                float m1 = t1v * X0 * INV_AVG_NN;
                a0 += m0;
                ax = fmaf(m1, sY1[el][0], ax);
                ay = fmaf(m1, sY1[el][1], ay);
                az = fmaf(m1, sY1[el][2], az);
            }
            atomicAdd(&M0[r_cur * 64 + cc], a0);
            atomicAdd(&M1[r_cur * 192 + cc], ax);
            atomicAdd(&M1[r_cur * 192 + 64 + cc], ay);
            atomicAdd(&M1[r_cur * 192 + 128 + cc], az);
        }
        __syncthreads();  // sTP reads done before next phase overwrites it
    }
}

// ---------------------------------------------------------------------------
// Edge kernel: 64 edges per 320-thread block. BYTE-IDENTICAL to the round-6
// version (602 us; r9-r12 confirmed binary stability across TU changes).
// Frozen: r7/r8 perturbations cost 95-240 us. Consumes the ORIGINAL
// unsorted eidx (r12 proved sort order is timing-neutral for it).
__global__ __launch_bounds__(320, 4) void k_edge(
    const float* __restrict__ pos, const int* __restrict__ eidx,
    const float* __restrict__ x0, const float* __restrict__ x1,
    const float* __restrict__ W1, const float* __restrict__ W2,
    const float* __restrict__ W3,
    float* __restrict__ M0, float* __restrict__ M1, int nedges) {
    __shared__ __align__(16) float sFEAT[64][8];
    __shared__ float sY1[64][3];
    __shared__ int sSend[64];
    __shared__ int sRecv[64];
    __shared__ __align__(16) float sH2[64 * 68];  // pad 68: b128 rows, banks spread
    __shared__ __align__(16) float sU[5440];      // union: sH1T[64*68] | sTP[5*16*68]

    float* const sH1T = sU;  // [k][edge], stride 68
    float* const sTP = sU;   // [5][16][68]

    const int t = threadIdx.x;
    const int eb = t & 7;          // GEMM: edge sub-index (edges i*8+eb)
    const int cb8 = (t >> 3) * 8;  // GEMM: first owned tpw column (0..312)
    const int wv = t >> 6;         // wave index == path index of owned cols
    const int c0 = cb8 & 63;       // channel offset within path block

    // ---- P0: geometry + radial features (fp64 for accuracy), threads 0..63
    if (t < 64) {
        int e = blockIdx.x * 64 + t;
        int s = 0, r = 0;
        float y0 = 0.f, y1 = 0.f, y2 = 0.f;
        float feats[NBES];
#pragma unroll
        for (int b = 0; b < NBES; ++b) feats[b] = 0.f;
        if (e < nedges) {
            s = eidx[e];
            r = eidx[nedges + e];
            double dx = (double)pos[3 * s + 0] - (double)pos[3 * r + 0];
            double dy = (double)pos[3 * s + 1] - (double)pos[3 * r + 1];
            double dz = (double)pos[3 * s + 2] - (double)pos[3 * r + 2];
            double rr = sqrt(dx * dx + dy * dy + dz * dz);
            if (rr < 1e-6) rr = 1e-6;
            double inv = 1.0 / rr;
            y0 = (float)(1.7320508075688772 * dx * inv);
            y1 = (float)(1.7320508075688772 * dy * inv);
            y2 = (float)(1.7320508075688772 * dz * inv);
            double xx = rr * 0.2;  // r / R_MAX
            double f = 0.0;
            if (xx < 1.0) {
                double x2 = xx * xx, x3 = x2 * xx, x6 = x3 * x3;
                f = 1.0 - 28.0 * x6 + 48.0 * x6 * xx - 21.0 * x6 * x2;
            }
            double pref = 0.63245553203367587 * f * inv;  // sqrt(2/R_MAX)
#pragma unroll
            for (int b = 0; b < NBES; ++b) {
                double arg = (double)(b + 1) * 3.14159265358979324 * rr * 0.2;
                feats[b] = (float)(sin(arg) * pref);
            }
        }
        sSend[t] = s;
        sRecv[t] = r;
        sY1[t][0] = y0; sY1[t][1] = y1; sY1[t][2] = y2;
#pragma unroll
        for (int b = 0; b < NBES; ++b) sFEAT[t][b] = feats[b];
    }
    __syncthreads();

    // ---- P1: hid1 = silu(feat @ W1) -> sH1T[k][edge] (transposed, stride 68)
    if (t < 256) {
        const int j = t & 63;
        float w1c[NBES];
#pragma unroll
        for (int b = 0; b < NBES; ++b) w1c[b] = W1[b * 64 + j];
#pragma unroll
        for (int i = 0; i < 16; ++i) {
            int el = wv * 16 + i;
            const float4* fr = (const float4*)(&sFEAT[el][0]);  // broadcast reads
            float4 f0 = fr[0], f1 = fr[1];
            float acc = 0.f;
            acc = fmaf(f0.x, w1c[0], acc);
            acc = fmaf(f0.y, w1c[1], acc);
            acc = fmaf(f0.z, w1c[2], acc);
            acc = fmaf(f0.w, w1c[3], acc);
            acc = fmaf(f1.x, w1c[4], acc);
            acc = fmaf(f1.y, w1c[5], acc);
            acc = fmaf(f1.z, w1c[6], acc);
            acc = fmaf(f1.w, w1c[7], acc);
            sH1T[j * 68 + el] = silu(acc);
        }
    }
    __syncthreads();

    // ---- P2: hid2 = silu(hid1 @ W2), 4 edges x 4 cols per thread,
    // A from sH1T (b128), B from global W2 (L1-resident, 16KB).
    if (t < 256) {
        const int eg = t >> 4;         // edge group: edges 4*eg..+4
        const int j4 = (t & 15) * 4;   // col group: cols j4..j4+4
        float a00 = 0.f, a01 = 0.f, a02 = 0.f, a03 = 0.f;
        float a10 = 0.f, a11 = 0.f, a12 = 0.f, a13 = 0.f;
        float a20 = 0.f, a21 = 0.f, a22 = 0.f, a23 = 0.f;
        float a30 = 0.f, a31 = 0.f, a32 = 0.f, a33 = 0.f;
#pragma unroll 4
        for (int k = 0; k < 64; ++k) {
            float4 av = *(const float4*)&sH1T[k * 68 + 4 * eg];
            float4 wv4 = *(const float4*)&W2[k * 64 + j4];
            a00 = fmaf(av.x, wv4.x, a00); a01 = fmaf(av.x, wv4.y, a01);
            a02 = fmaf(av.x, wv4.z, a02); a03 = fmaf(av.x, wv4.w, a03);
            a10 = fmaf(av.y, wv4.x, a10); a11 = fmaf(av.y, wv4.y, a11);
            a12 = fmaf(av.y, wv4.z, a12); a13 = fmaf(av.y, wv4.w, a13);
            a20 = fmaf(av.z, wv4.x, a20); a21 = fmaf(av.z, wv4.y, a21);
            a22 = fmaf(av.z, wv4.z, a22); a23 = fmaf(av.z, wv4.w, a23);
            a30 = fmaf(av.w, wv4.x, a30); a31 = fmaf(av.w, wv4.y, a31);
            a32 = fmaf(av.w, wv4.z, a32); a33 = fmaf(av.w, wv4.w, a33);
        }
        *(float4*)&sH2[(4 * eg + 0) * 68 + j4] =
            make_float4(silu(a00), silu(a01), silu(a02), silu(a03));
        *(float4*)&sH2[(4 * eg + 1) * 68 + j4] =
            make_float4(silu(a10), silu(a11), silu(a12), silu(a13));
        *(float4*)&sH2[(4 * eg + 2) * 68 + j4] =
            make_float4(silu(a20), silu(a21), silu(a22), silu(a23));
        *(float4*)&sH2[(4 * eg + 3) * 68 + j4] =
            make_float4(silu(a30), silu(a31), silu(a32), silu(a33));
    }
    __syncthreads();  // sH2 ready; sH1T dead -> union free for sTP

    // ---- P3: barrier-free GEMM
    // acc[i][j] = sum_k sH2[i*8+eb][k] * W3[k][cb8+j]; W3 via VMEM (L2-hot)
    float acc[8][8];
#pragma unroll
    for (int i = 0; i < 8; ++i)
#pragma unroll
        for (int j = 0; j < 8; ++j) acc[i][j] = 0.f;

#pragma unroll 1
    for (int kt = 0; kt < 16; ++kt) {  // K-step 4
        float4 h[8];
#pragma unroll
        for (int i = 0; i < 8; ++i)
            h[i] = *(const float4*)&sH2[(i * 8 + eb) * 68 + kt * 4];
#pragma unroll
        for (int kk = 0; kk < 4; ++kk) {
            const int k = kt * 4 + kk;
            float4 wa = *(const float4*)&W3[k * 320 + cb8];
            float4 wb = *(const float4*)&W3[k * 320 + cb8 + 4];
#pragma unroll
            for (int i = 0; i < 8; ++i) {
                float hv = (kk == 0) ? h[i].x
                         : (kk == 1) ? h[i].y
                         : (kk == 2) ? h[i].z
                                     : h[i].w;
                acc[i][0] = fmaf(hv, wa.x, acc[i][0]);
                acc[i][1] = fmaf(hv, wa.y, acc[i][1]);
                acc[i][2] = fmaf(hv, wa.z, acc[i][2]);
                acc[i][3] = fmaf(hv, wa.w, acc[i][3]);
                acc[i][4] = fmaf(hv, wb.x, acc[i][4]);
                acc[i][5] = fmaf(hv, wb.y, acc[i][5]);
                acc[i][6] = fmaf(hv, wb.z, acc[i][6]);
                acc[i][7] = fmaf(hv, wb.w, acc[i][7]);
            }
        }
    }

    // ---- P4: 4 message phases, 16 edges each. Thread stages acc[2g][*]
    // (edge g*16+eb) and acc[2g+1][*] (edge g*16+8+eb) into sTP[p][el][ch].
#pragma unroll
    for (int g = 0; g < 4; ++g) {
        {
            const int rowA = (wv * 16 + eb) * 68 + c0;
            const int rowB = (wv * 16 + 8 + eb) * 68 + c0;
            *(float4*)&sTP[rowA] =
                make_float4(acc[2 * g][0], acc[2 * g][1], acc[2 * g][2], acc[2 * g][3]);
            *(float4*)&sTP[rowA + 4] =
                make_float4(acc[2 * g][4], acc[2 * g][5], acc[2 * g][6], acc[2 * g][7]);
            *(float4*)&sTP[rowB] =
                make_float4(acc[2 * g + 1][0], acc[2 * g + 1][1], acc[2 * g + 1][2], acc[2 * g + 1][3]);
            *(float4*)&sTP[rowB + 4] =
                make_float4(acc[2 * g + 1][4], acc[2 * g + 1][5], acc[2 * g + 1][6], acc[2 * g + 1][7]);
        }
        __syncthreads();  // tpw staged
        // 16 edges x 64 channels = 1024 items over 320 threads
        for (int v = t; v < 1024; v += 320) {
            int i = v >> 6, cc = v & 63;
            int el = g * 16 + i;
            int s = sSend[el], r = sRecv[el];
            float X0 = x0[s * 64 + cc];
            float Xx = x1[s * 192 + cc];
            float Xy = x1[s * 192 + 64 + cc];
            float Xz = x1[s * 192 + 128 + cc];
            float Yx = sY1[el][0], Yy = sY1[el][1], Yz = sY1[el][2];
            float t0 = sTP[(0 * 16 + i) * 68 + cc];
            float t1 = sTP[(1 * 16 + i) * 68 + cc];
            float t2 = sTP[(2 * 16 + i) * 68 + cc];
            float t3 = sTP[(3 * 16 + i) * 68 + cc];
            float t4 = sTP[(4 * 16 + i) * 68 + cc];
            float dotp = Xx * Yx + Xy * Yy + Xz * Yz;
            float m0 = t0 * X0 + t3 * (dotp * INV_SQRT3_F);
            float cx = Xy * Yz - Xz * Yy;
            float cy = Xz * Yx - Xx * Yz;
            float cz = Xx * Yy - Xy * Yx;
            float m1x = t1 * X0 * Yx + t2 * Xx + t4 * (cx * INV_SQRT2_F);
            float m1y = t1 * X0 * Yy + t2 * Xy + t4 * (cy * INV_SQRT2_F);
            float m1z = t1 * X0 * Yz + t2 * Xz + t4 * (cz * INV_SQRT2_F);
            atomicAdd(&M0[r * 64 + cc], m0 * INV_AVG_NN);
            atomicAdd(&M1[r * 192 + cc], m1x * INV_AVG_NN);
            atomicAdd(&M1[r * 192 + 64 + cc], m1y * INV_AVG_NN);
            atomicAdd(&M1[r * 192 + 128 + cc], m1z * INV_AVG_NN);
        }
        __syncthreads();  // sTP reads done before next phase overwrites it
    }
}

// ---------------------------------------------------------------------------
// Fused layer-0 node update + layer-1 lin_up. (unchanged from round 11)
__global__ __launch_bounds__(256) void k_nodelin(
    float* __restrict__ h0, float* __restrict__ h1,
    const int* __restrict__ species,
    const float* __restrict__ linW0, const float* __restrict__ linW1,
    const float* __restrict__ prodW0, const float* __restrict__ prodW1,
    const float* __restrict__ plinW0, const float* __restrict__ plinW1,
    const float* __restrict__ lupW0, const float* __restrict__ lupW1,
    float* __restrict__ x0, float* __restrict__ x1, int nnodes) {
    __shared__ float sh[4][4][64];
    const int w = threadIdx.x >> 6, k = threadIdx.x & 63;
    const int n = blockIdx.x * 4 + w;
    const bool valid = n < nnodes;
    float v0 = valid ? h0[n * 64 + k] : 0.f;
    float v1 = valid ? h1[n * 192 + k] : 0.f;
    float v2 = valid ? h1[n * 192 + 64 + k] : 0.f;
    float v3 = valid ? h1[n * 192 + 128 + k] : 0.f;
    sh[w][0][k] = v0; sh[w][1][k] = v1; sh[w][2][k] = v2; sh[w][3][k] = v3;
    if (valid) {  // zero scatter accumulators for layer 1
        h0[n * 64 + k] = 0.f;
        h1[n * 192 + k] = 0.f;
        h1[n * 192 + 64 + k] = 0.f;
        h1[n * 192 + 128 + k] = 0.f;
    }
    __syncthreads();
    float a0 = 0.f, a1 = 0.f, a2 = 0.f, a3 = 0.f;
    for (int c = 0; c < 64; ++c) {
        float w0 = linW0[c * 64 + k], w1 = linW1[c * 64 + k];
        a0 = fmaf(sh[w][0][c], w0, a0);
        a1 = fmaf(sh[w][1][c], w1, a1);
        a2 = fmaf(sh[w][2][c], w1, a2);
        a3 = fmaf(sh[w][3][c], w1, a3);
    }
    int sp = valid ? species[n] : 0;
    float p00 = prodW0[sp * 192 + k];
    float p01 = prodW0[sp * 192 + 64 + k];
    float p02 = prodW0[sp * 192 + 128 + k];
    float p10 = prodW1[sp * 128 + k];
    float p11 = prodW1[sp * 128 + 64 + k];
    float nsq = a1 * a1 + a2 * a2 + a3 * a3;
    float b0 = p00 * a0 + p01 * (a0 * a0) + p02 * (nsq * INV_SQRT3_F);
    float b1x = p10 * a1 + p11 * (a0 * a1);
    float b1y = p10 * a2 + p11 * (a0 * a2);
    float b1z = p10 * a3 + p11 * (a0 * a3);
    __syncthreads();
    sh[w][0][k] = b0; sh[w][1][k] = b1x; sh[w][2][k] = b1y; sh[w][3][k] = b1z;
    __syncthreads();
    a0 = a1 = a2 = a3 = 0.f;
    for (int c = 0; c < 64; ++c) {
        float w0 = plinW0[c * 64 + k], w1 = plinW1[c * 64 + k];
        a0 = fmaf(sh[w][0][c], w0, a0);
        a1 = fmaf(sh[w][1][c], w1, a1);
        a2 = fmaf(sh[w][2][c], w1, a2);
        a3 = fmaf(sh[w][3][c], w1, a3);
    }
    __syncthreads();
    sh[w][0][k] = a0; sh[w][1][k] = a1; sh[w][2][k] = a2; sh[w][3][k] = a3;
    __syncthreads();
    a0 = a1 = a2 = a3 = 0.f;
    for (int c = 0; c < 64; ++c) {
        float w0 = lupW0[c * 64 + k], w1 = lupW1[c * 64 + k];
        a0 = fmaf(sh[w][0][c], w0, a0);
        a1 = fmaf(sh[w][1][c], w1, a1);
        a2 = fmaf(sh[w][2][c], w1, a2);
        a3 = fmaf(sh[w][3][c], w1, a3);
    }
    if (valid) {
        x0[n * 64 + k] = a0;
        x1[n * 192 + k] = a1;
        x1[n * 192 + 64 + k] = a2;
        x1[n * 192 + 128 + k] = a3;
    }
}

// ---------------------------------------------------------------------------
// Fused layer-1 node update + output write. (unchanged from round 11)
__global__ __launch_bounds__(256) void k_nodeout(
    const float* __restrict__ h0, const float* __restrict__ h1,
    const int* __restrict__ species,
    const float* __restrict__ linW0, const float* __restrict__ linW1,
    const float* __restrict__ prodW0, const float* __restrict__ prodW1,
    const float* __restrict__ plinW0, const float* __restrict__ plinW1,
    float4* __restrict__ out, int nnodes) {
    __shared__ float sh[4][4][64];
    const int w = threadIdx.x >> 6, k = threadIdx.x & 63;
    const int n = blockIdx.x * 4 + w;
    const bool valid = n < nnodes;
    float v0 = valid ? h0[n * 64 + k] : 0.f;
    float v1 = valid ? h1[n * 192 + k] : 0.f;
    float v2 = valid ? h1[n * 192 + 64 + k] : 0.f;
    float v3 = valid ? h1[n * 192 + 128 + k] : 0.f;
    sh[w][0][k] = v0; sh[w][1][k] = v1; sh[w][2][k] = v2; sh[w][3][k] = v3;
    __syncthreads();
    float a0 = 0.f, a1 = 0.f, a2 = 0.f, a3 = 0.f;
    for (int c = 0; c < 64; ++c) {
        float w0 = linW0[c * 64 + k], w1 = linW1[c * 64 + k];
        a0 = fmaf(sh[w][0][c], w0, a0);
        a1 = fmaf(sh[w][1][c], w1, a1);
        a2 = fmaf(sh[w][2][c], w1, a2);
        a3 = fmaf(sh[w][3][c], w1, a3);
    }
    int sp = valid ? species[n] : 0;
    float p00 = prodW0[sp * 192 + k];
    float p01 = prodW0[sp * 192 + 64 + k];
    float p02 = prodW0[sp * 192 + 128 + k];
    float p10 = prodW1[sp * 128 + k];
    float p11 = prodW1[sp * 128 + 64 + k];
    float nsq = a1 * a1 + a2 * a2 + a3 * a3;
    float b0 = p00 * a0 + p01 * (a0 * a0) + p02 * (nsq * INV_SQRT3_F);
    float b1x = p10 * a1 + p11 * (a0 * a1);
    float b1y = p10 * a2 + p11 * (a0 * a2);
    float b1z = p10 * a3 + p11 * (a0 * a3);
    __syncthreads();
    sh[w][0][k] = b0; sh[w][1][k] = b1x; sh[w][2][k] = b1y; sh[w][3][k] = b1z;
    __syncthreads();
    a0 = a1 = a2 = a3 = 0.f;
    for (int c = 0; c < 64; ++c) {
        float w0 = plinW0[c * 64 + k], w1 = plinW1[c * 64 + k];
        a0 = fmaf(sh[w][0][c], w0, a0);
        a1 = fmaf(sh[w][1][c], w1, a1);
        a2 = fmaf(sh[w][2][c], w1, a2);
        a3 = fmaf(sh[w][3][c], w1, a3);
    }
    if (valid) out[n * 64 + k] = make_float4(a0, a1, a2, a3);
}

// ---------------------------------------------------------------------------
extern "C" void kernel_launch(void* const* d_in, const int* in_sizes, int n_in,
                              void* d_out, int out_size, void* d_ws,
                              size_t ws_size, hipStream_t stream) {
    const float* positions = (const float*)d_in[0];
    const int* species = (const int*)d_in[1];
    const int* eidx = (const int*)d_in[2];
    const float* embedW = (const float*)d_in[3];
    const float* linupW0 = (const float*)d_in[4];
    const float* linupW1 = (const float*)d_in[5];
    const float* mlpW1 = (const float*)d_in[6];
    const float* mlpW2 = (const float*)d_in[7];
    const float* mlpW3 = (const float*)d_in[8];
    const float* linW0 = (const float*)d_in[9];
    const float* linW1 = (const float*)d_in[10];
    const float* prodW0 = (const float*)d_in[11];
    const float* prodW1 = (const float*)d_in[12];
    const float* plinW0 = (const float*)d_in[13];
    const float* plinW1 = (const float*)d_in[14];

    const int nn = in_sizes[0] / 3;   // 25000
    const int ne = in_sizes[2] / 2;   // 400000

    // workspace layout (floats): h0 | h1 | x0 | x1 | eidx2(int)
    float* h0 = (float*)d_ws;
    float* h1 = h0 + (size_t)nn * 64;
    float* x0 = h1 + (size_t)nn * 192;
    float* x1 = x0 + (size_t)nn * 64;
    int* eidx2 = (int*)(x1 + (size_t)nn * 192);

    const int gridNode = (nn + 3) / 4;
    const int gridEdge = (ne + 63) / 64;
    const int gridE256 = (ne + 255) / 256;

    // ---- receiver-sort the edge list (for k_edge0's merged message phase).
    // cnt aliases x1 (dead until k_nodelin). Guard on workspace capacity;
    // fall back to unsorted edges (merge still correct, just fewer merges).
    const size_t needed =
        ((size_t)nn * 512) * sizeof(float) + (size_t)2 * ne * sizeof(int);
    const int* eidx0_use = eidx;
    if (ws_size >= needed) {
        int* cnt = (int*)x1;
        hipMemsetAsync(cnt, 0, (size_t)nn * sizeof(int), stream);
        k_hist<<<gridE256, 256, 0, stream>>>(eidx, cnt, ne);
        k_scan<<<1, 1024, 0, stream>>>(cnt, nn);
        k_scatter<<<gridE256, 256, 0, stream>>>(eidx, cnt, eidx2, ne);
        eidx0_use = eidx2;
    }

    // ---- layer 0 (k_edge0 consumes receiver-sorted edges -> merged atomics)
    k_lin0<<<gridNode, 256, 0, stream>>>(
        h0, h1, species, embedW, linupW0, x0, nn);
    k_edge0<<<gridEdge, 320, 0, stream>>>(
        positions, eidx0_use, x0, mlpW1, mlpW2, mlpW3, h0, h1, ne);

    // ---- layer-0 node update fused with layer-1 lin_up
    k_nodelin<<<gridNode, 256, 0, stream>>>(
        h0, h1, species, linW0, linW1, prodW0, prodW1, plinW0, plinW1,
        linupW0 + 4096, linupW1 + 4096, x0, x1, nn);

    // ---- layer 1: frozen general edge kernel, ORIGINAL unsorted edges
    k_edge<<<gridEdge, 320, 0, stream>>>(
        positions, eidx, x0, x1, mlpW1 + 512, mlpW2 + 4096,
        mlpW3 + 20480, h0, h1, ne);

    // ---- layer-1 node update fused with output write
    k_nodeout<<<gridNode, 256, 0, stream>>>(
        h0, h1, species, linW0 + 4096, linW1 + 4096,
        prodW0 + 768, prodW1 + 512, plinW0 + 4096, plinW1 + 4096,
        (float4*)d_out, nn);
}

// Round 14
// 1072.449 us; speedup vs baseline: 1.1685x; 1.0563x over previous
//
#include <hip/hip_runtime.h>
#include <math.h>

// Problem constants (C, HID, etc. are structural; N and E taken from in_sizes)
#define CDIM 64
#define NBES 8

#define SQRT3_F     1.7320508075688772f
#define INV_SQRT3_F 0.57735026918962576f
#define INV_SQRT2_F 0.70710678118654752f
#define INV_AVG_NN  0.0625f

__device__ __forceinline__ float silu(float x) {
    return x / (1.0f + expf(-x));
}

// ---------------------------------------------------------------------------
// Counting sort of the edge list by RECEIVER. r12 proved gathers are fully
// latency-hidden (sort order free on the gather side); receiver-sorting
// makes same-receiver edges contiguous, enabling in-register atomic MERGING
// in the message phase (~3.2x fewer atomics; r13 verified -90us on the
// layer-0 kernel). Both layers now consume the sorted list (sort amortized).

__global__ __launch_bounds__(256) void k_hist(const int* __restrict__ eidx,
                                              int* __restrict__ cnt, int ne) {
    int e = blockIdx.x * 256 + threadIdx.x;
    if (e < ne) atomicAdd(&cnt[eidx[ne + e]], 1);
}

// Single-block exclusive scan over nn counters (in place).
__global__ __launch_bounds__(1024) void k_scan(int* __restrict__ cnt, int nn) {
    __shared__ int part[1024];
    const int t = threadIdx.x;
    const int chunk = (nn + 1023) / 1024;
    const int lo = t * chunk;
    const int hi = min(lo + chunk, nn);
    int sum = 0;
    for (int i = lo; i < hi; ++i) sum += cnt[i];
    part[t] = sum;
    __syncthreads();
    for (int off = 1; off < 1024; off <<= 1) {
        int v = (t >= off) ? part[t - off] : 0;
        __syncthreads();
        part[t] += v;
        __syncthreads();
    }
    int run = (t == 0) ? 0 : part[t - 1];  // exclusive base of this chunk
    for (int i = lo; i < hi; ++i) {
        int c = cnt[i];
        cnt[i] = run;
        run += c;
    }
}

__global__ __launch_bounds__(256) void k_scatter(const int* __restrict__ eidx,
                                                 int* __restrict__ cnt,
                                                 int* __restrict__ eidx2,
                                                 int ne) {
    int e = blockIdx.x * 256 + threadIdx.x;
    if (e < ne) {
        int r = eidx[ne + e];
        int p = atomicAdd(&cnt[r], 1);
        eidx2[p] = eidx[e];   // sender
        eidx2[ne + p] = r;    // receiver (sort key)
    }
}

// ---------------------------------------------------------------------------
// Layer-0 front end, fully fused: x0 = embed[species] @ W0 computed straight
// from the embedding table (wave-uniform row), h0/h1 zeroed as scatter
// accumulators. x1 is NOT computed (h1==0 at layer 0).
__global__ __launch_bounds__(256) void k_lin0(
    float* __restrict__ h0, float* __restrict__ h1,
    const int* __restrict__ species, const float* __restrict__ embedW,
    const float* __restrict__ W0, float* __restrict__ x0, int nnodes) {
    const int w = threadIdx.x >> 6, k = threadIdx.x & 63;
    const int n = blockIdx.x * 4 + w;
    if (n >= nnodes) return;
    const float* er = embedW + species[n] * 64;  // wave-uniform
    float a0 = 0.f;
    for (int c = 0; c < 64; ++c) a0 = fmaf(er[c], W0[c * 64 + k], a0);
    x0[n * 64 + k] = a0;
    h0[n * 64 + k] = 0.f;
    h1[n * 192 + k] = 0.f;
    h1[n * 192 + 64 + k] = 0.f;
    h1[n * 192 + 128 + k] = 0.f;
}

// ---------------------------------------------------------------------------
// LAYER-0 edge kernel with merged atomics. BYTE-IDENTICAL to round 13
// (~340 us verified). Frozen.
__global__ __launch_bounds__(320, 4) void k_edge0(
    const float* __restrict__ pos, const int* __restrict__ eidx,
    const float* __restrict__ x0,
    const float* __restrict__ W1, const float* __restrict__ W2,
    const float* __restrict__ W3,
    float* __restrict__ M0, float* __restrict__ M1, int nedges) {
    __shared__ __align__(16) float sFEAT[64][8];
    __shared__ float sY1[64][3];
    __shared__ int sSend[64];
    __shared__ int sRecv[64];
    __shared__ __align__(16) float sH2[64 * 68];
    __shared__ __align__(16) float sU0[4352];  // union: sH1T[64*68] | sTP[2][16][68]

    float* const sH1T = sU0;  // [k][edge], stride 68
    float* const sTP = sU0;   // [2][16][68]

    const int t = threadIdx.x;
    const int wv = t >> 6;

    // ---- P0: geometry + radial features (fp64 for accuracy), threads 0..63
    if (t < 64) {
        int e = blockIdx.x * 64 + t;
        int s = 0, r = 0;
        float y0 = 0.f, y1 = 0.f, y2 = 0.f;
        float feats[NBES];
#pragma unroll
        for (int b = 0; b < NBES; ++b) feats[b] = 0.f;
        if (e < nedges) {
            s = eidx[e];
            r = eidx[nedges + e];
            double dx = (double)pos[3 * s + 0] - (double)pos[3 * r + 0];
            double dy = (double)pos[3 * s + 1] - (double)pos[3 * r + 1];
            double dz = (double)pos[3 * s + 2] - (double)pos[3 * r + 2];
            double rr = sqrt(dx * dx + dy * dy + dz * dz);
            if (rr < 1e-6) rr = 1e-6;
            double inv = 1.0 / rr;
            y0 = (float)(1.7320508075688772 * dx * inv);
            y1 = (float)(1.7320508075688772 * dy * inv);
            y2 = (float)(1.7320508075688772 * dz * inv);
            double xx = rr * 0.2;  // r / R_MAX
            double f = 0.0;
            if (xx < 1.0) {
                double x2 = xx * xx, x3 = x2 * xx, x6 = x3 * x3;
                f = 1.0 - 28.0 * x6 + 48.0 * x6 * xx - 21.0 * x6 * x2;
            }
            double pref = 0.63245553203367587 * f * inv;  // sqrt(2/R_MAX)
#pragma unroll
            for (int b = 0; b < NBES; ++b) {
                double arg = (double)(b + 1) * 3.14159265358979324 * rr * 0.2;
                feats[b] = (float)(sin(arg) * pref);
            }
        }
        sSend[t] = s;
        sRecv[t] = r;
        sY1[t][0] = y0; sY1[t][1] = y1; sY1[t][2] = y2;
#pragma unroll
        for (int b = 0; b < NBES; ++b) sFEAT[t][b] = feats[b];
    }
    __syncthreads();

    // ---- P1: hid1 = silu(feat @ W1) -> sH1T[k][edge] (transposed, stride 68)
    if (t < 256) {
        const int j = t & 63;
        float w1c[NBES];
#pragma unroll
        for (int b = 0; b < NBES; ++b) w1c[b] = W1[b * 64 + j];
#pragma unroll
        for (int i = 0; i < 16; ++i) {
            int el = wv * 16 + i;
            const float4* fr = (const float4*)(&sFEAT[el][0]);
            float4 f0 = fr[0], f1 = fr[1];
            float acc = 0.f;
            acc = fmaf(f0.x, w1c[0], acc);
            acc = fmaf(f0.y, w1c[1], acc);
            acc = fmaf(f0.z, w1c[2], acc);
            acc = fmaf(f0.w, w1c[3], acc);
            acc = fmaf(f1.x, w1c[4], acc);
            acc = fmaf(f1.y, w1c[5], acc);
            acc = fmaf(f1.z, w1c[6], acc);
            acc = fmaf(f1.w, w1c[7], acc);
            sH1T[j * 68 + el] = silu(acc);
        }
    }
    __syncthreads();

    // ---- P2: hid2 = silu(hid1 @ W2), 4 edges x 4 cols per thread
    if (t < 256) {
        const int eg = t >> 4;
        const int j4 = (t & 15) * 4;
        float a00 = 0.f, a01 = 0.f, a02 = 0.f, a03 = 0.f;
        float a10 = 0.f, a11 = 0.f, a12 = 0.f, a13 = 0.f;
        float a20 = 0.f, a21 = 0.f, a22 = 0.f, a23 = 0.f;
        float a30 = 0.f, a31 = 0.f, a32 = 0.f, a33 = 0.f;
#pragma unroll 4
        for (int k = 0; k < 64; ++k) {
            float4 av = *(const float4*)&sH1T[k * 68 + 4 * eg];
            float4 wv4 = *(const float4*)&W2[k * 64 + j4];
            a00 = fmaf(av.x, wv4.x, a00); a01 = fmaf(av.x, wv4.y, a01);
            a02 = fmaf(av.x, wv4.z, a02); a03 = fmaf(av.x, wv4.w, a03);
            a10 = fmaf(av.y, wv4.x, a10); a11 = fmaf(av.y, wv4.y, a11);
            a12 = fmaf(av.y, wv4.z, a12); a13 = fmaf(av.y, wv4.w, a13);
            a20 = fmaf(av.z, wv4.x, a20); a21 = fmaf(av.z, wv4.y, a21);
            a22 = fmaf(av.z, wv4.z, a22); a23 = fmaf(av.z, wv4.w, a23);
            a30 = fmaf(av.w, wv4.x, a30); a31 = fmaf(av.w, wv4.y, a31);
            a32 = fmaf(av.w, wv4.z, a32); a33 = fmaf(av.w, wv4.w, a33);
        }
        *(float4*)&sH2[(4 * eg + 0) * 68 + j4] =
            make_float4(silu(a00), silu(a01), silu(a02), silu(a03));
        *(float4*)&sH2[(4 * eg + 1) * 68 + j4] =
            make_float4(silu(a10), silu(a11), silu(a12), silu(a13));
        *(float4*)&sH2[(4 * eg + 2) * 68 + j4] =
            make_float4(silu(a20), silu(a21), silu(a22), silu(a23));
        *(float4*)&sH2[(4 * eg + 3) * 68 + j4] =
            make_float4(silu(a30), silu(a31), silu(a32), silu(a33));
    }
    __syncthreads();  // sH2 ready; sH1T dead -> union free for sTP

    // ---- P3: GEMM over tpw paths 0,1 only (cols 0..127).
    const int eb16 = t & 15;
    const int cb8 = (t >> 4) * 8;  // 0..120 for t<256
    float acc[4][8];
#pragma unroll
    for (int i = 0; i < 4; ++i)
#pragma unroll
        for (int j = 0; j < 8; ++j) acc[i][j] = 0.f;

    if (t < 256) {
#pragma unroll 1
        for (int kt = 0; kt < 16; ++kt) {
            float4 h[4];
#pragma unroll
            for (int i = 0; i < 4; ++i)
                h[i] = *(const float4*)&sH2[(i * 16 + eb16) * 68 + kt * 4];
#pragma unroll
            for (int kk = 0; kk < 4; ++kk) {
                const int k = kt * 4 + kk;
                float4 wa = *(const float4*)&W3[k * 320 + cb8];
                float4 wb = *(const float4*)&W3[k * 320 + cb8 + 4];
#pragma unroll
                for (int i = 0; i < 4; ++i) {
                    float hv = (kk == 0) ? h[i].x
                             : (kk == 1) ? h[i].y
                             : (kk == 2) ? h[i].z
                                         : h[i].w;
                    acc[i][0] = fmaf(hv, wa.x, acc[i][0]);
                    acc[i][1] = fmaf(hv, wa.y, acc[i][1]);
                    acc[i][2] = fmaf(hv, wa.z, acc[i][2]);
                    acc[i][3] = fmaf(hv, wa.w, acc[i][3]);
                    acc[i][4] = fmaf(hv, wb.x, acc[i][4]);
                    acc[i][5] = fmaf(hv, wb.y, acc[i][5]);
                    acc[i][6] = fmaf(hv, wb.z, acc[i][6]);
                    acc[i][7] = fmaf(hv, wb.w, acc[i][7]);
                }
            }
        }
    }

    // ---- P4: 4 message phases, 16 contiguous receiver-sorted edges each.
    const int p0 = cb8 >> 6;
    const int c0 = cb8 & 63;
#pragma unroll
    for (int g = 0; g < 4; ++g) {
        if (t < 256) {
            const int row = (p0 * 16 + eb16) * 68 + c0;
            *(float4*)&sTP[row] =
                make_float4(acc[g][0], acc[g][1], acc[g][2], acc[g][3]);
            *(float4*)&sTP[row + 4] =
                make_float4(acc[g][4], acc[g][5], acc[g][6], acc[g][7]);
        }
        __syncthreads();  // tpw staged
        if (t < 256) {
            const int q = t >> 6, cc = t & 63;
            int r_cur = -1;
            float a0 = 0.f, ax = 0.f, ay = 0.f, az = 0.f;
#pragma unroll
            for (int j = 0; j < 4; ++j) {
                int i = q * 4 + j;
                int el = g * 16 + i;
                int s = sSend[el], r = sRecv[el];
                if (r != r_cur) {  // wave-uniform branch (one wave = one q)
                    if (r_cur >= 0) {
                        atomicAdd(&M0[r_cur * 64 + cc], a0);
                        atomicAdd(&M1[r_cur * 192 + cc], ax);
                        atomicAdd(&M1[r_cur * 192 + 64 + cc], ay);
                        atomicAdd(&M1[r_cur * 192 + 128 + cc], az);
                    }
                    r_cur = r;
                    a0 = ax = ay = az = 0.f;
                }
                float X0 = x0[s * 64 + cc];
                float t0v = sTP[(0 * 16 + i) * 68 + cc];
                float t1v = sTP[(1 * 16 + i) * 68 + cc];
                float m0 = t0v * X0 * INV_AVG_NN;
                float m1 = t1v * X0 * INV_AVG_NN;
                a0 += m0;
                ax = fmaf(m1, sY1[el][0], ax);
                ay = fmaf(m1, sY1[el][1], ay);
                az = fmaf(m1, sY1[el][2], az);
            }
            atomicAdd(&M0[r_cur * 64 + cc], a0);
            atomicAdd(&M1[r_cur * 192 + cc], ax);
            atomicAdd(&M1[r_cur * 192 + 64 + cc], ay);
            atomicAdd(&M1[r_cur * 192 + 128 + cc], az);
        }
        __syncthreads();  // sTP reads done before next phase overwrites it
    }
}

// ---------------------------------------------------------------------------
// LAYER-1 edge kernel with merged atomics: P0-P3 textually identical to the
// frozen r6 k_edge; P4's message loop rewritten to the r13-PROVEN merge
// pattern (receiver-sorted edges, thread (q,cc) walks 4 contiguous edges,
// flushes 4 atomics only on receiver change -> ~3.2x fewer atomics, which
// r13 showed is worth ~90us on the identical atomic stream).
__global__ __launch_bounds__(320, 4) void k_edge1(
    const float* __restrict__ pos, const int* __restrict__ eidx,
    const float* __restrict__ x0, const float* __restrict__ x1,
    const float* __restrict__ W1, const float* __restrict__ W2,
    const float* __restrict__ W3,
    float* __restrict__ M0, float* __restrict__ M1, int nedges) {
    __shared__ __align__(16) float sFEAT[64][8];
    __shared__ float sY1[64][3];
    __shared__ int sSend[64];
    __shared__ int sRecv[64];
    __shared__ __align__(16) float sH2[64 * 68];  // pad 68: b128 rows, banks spread
    __shared__ __align__(16) float sU[5440];      // union: sH1T[64*68] | sTP[5*16*68]

    float* const sH1T = sU;  // [k][edge], stride 68
    float* const sTP = sU;   // [5][16][68]

    const int t = threadIdx.x;
    const int eb = t & 7;          // GEMM: edge sub-index (edges i*8+eb)
    const int cb8 = (t >> 3) * 8;  // GEMM: first owned tpw column (0..312)
    const int wv = t >> 6;         // wave index == path index of owned cols
    const int c0 = cb8 & 63;       // channel offset within path block

    // ---- P0: geometry + radial features (fp64 for accuracy), threads 0..63
    if (t < 64) {
        int e = blockIdx.x * 64 + t;
        int s = 0, r = 0;
        float y0 = 0.f, y1 = 0.f, y2 = 0.f;
        float feats[NBES];
#pragma unroll
        for (int b = 0; b < NBES; ++b) feats[b] = 0.f;
        if (e < nedges) {
            s = eidx[e];
            r = eidx[nedges + e];
            double dx = (double)pos[3 * s + 0] - (double)pos[3 * r + 0];
            double dy = (double)pos[3 * s + 1] - (double)pos[3 * r + 1];
            double dz = (double)pos[3 * s + 2] - (double)pos[3 * r + 2];
            double rr = sqrt(dx * dx + dy * dy + dz * dz);
            if (rr < 1e-6) rr = 1e-6;
            double inv = 1.0 / rr;
            y0 = (float)(1.7320508075688772 * dx * inv);
            y1 = (float)(1.7320508075688772 * dy * inv);
            y2 = (float)(1.7320508075688772 * dz * inv);
            double xx = rr * 0.2;  // r / R_MAX
            double f = 0.0;
            if (xx < 1.0) {
                double x2 = xx * xx, x3 = x2 * xx, x6 = x3 * x3;
                f = 1.0 - 28.0 * x6 + 48.0 * x6 * xx - 21.0 * x6 * x2;
            }
            double pref = 0.63245553203367587 * f * inv;  // sqrt(2/R_MAX)
#pragma unroll
            for (int b = 0; b < NBES; ++b) {
                double arg = (double)(b + 1) * 3.14159265358979324 * rr * 0.2;
                feats[b] = (float)(sin(arg) * pref);
            }
        }
        sSend[t] = s;
        sRecv[t] = r;
        sY1[t][0] = y0; sY1[t][1] = y1; sY1[t][2] = y2;
#pragma unroll
        for (int b = 0; b < NBES; ++b) sFEAT[t][b] = feats[b];
    }
    __syncthreads();

    // ---- P1: hid1 = silu(feat @ W1) -> sH1T[k][edge] (transposed, stride 68)
    if (t < 256) {
        const int j = t & 63;
        float w1c[NBES];
#pragma unroll
        for (int b = 0; b < NBES; ++b) w1c[b] = W1[b * 64 + j];
#pragma unroll
        for (int i = 0; i < 16; ++i) {
            int el = wv * 16 + i;
            const float4* fr = (const float4*)(&sFEAT[el][0]);  // broadcast reads
            float4 f0 = fr[0], f1 = fr[1];
            float acc = 0.f;
            acc = fmaf(f0.x, w1c[0], acc);
            acc = fmaf(f0.y, w1c[1], acc);
            acc = fmaf(f0.z, w1c[2], acc);
            acc = fmaf(f0.w, w1c[3], acc);
            acc = fmaf(f1.x, w1c[4], acc);
            acc = fmaf(f1.y, w1c[5], acc);
            acc = fmaf(f1.z, w1c[6], acc);
            acc = fmaf(f1.w, w1c[7], acc);
            sH1T[j * 68 + el] = silu(acc);
        }
    }
    __syncthreads();

    // ---- P2: hid2 = silu(hid1 @ W2), 4 edges x 4 cols per thread,
    // A from sH1T (b128), B from global W2 (L1-resident, 16KB).
    if (t < 256) {
        const int eg = t >> 4;         // edge group: edges 4*eg..+4
        const int j4 = (t & 15) * 4;   // col group: cols j4..j4+4
        float a00 = 0.f, a01 = 0.f, a02 = 0.f, a03 = 0.f;
        float a10 = 0.f, a11 = 0.f, a12 = 0.f, a13 = 0.f;
        float a20 = 0.f, a21 = 0.f, a22 = 0.f, a23 = 0.f;
        float a30 = 0.f, a31 = 0.f, a32 = 0.f, a33 = 0.f;
#pragma unroll 4
        for (int k = 0; k < 64; ++k) {
            float4 av = *(const float4*)&sH1T[k * 68 + 4 * eg];
            float4 wv4 = *(const float4*)&W2[k * 64 + j4];
            a00 = fmaf(av.x, wv4.x, a00); a01 = fmaf(av.x, wv4.y, a01);
            a02 = fmaf(av.x, wv4.z, a02); a03 = fmaf(av.x, wv4.w, a03);
            a10 = fmaf(av.y, wv4.x, a10); a11 = fmaf(av.y, wv4.y, a11);
            a12 = fmaf(av.y, wv4.z, a12); a13 = fmaf(av.y, wv4.w, a13);
            a20 = fmaf(av.z, wv4.x, a20); a21 = fmaf(av.z, wv4.y, a21);
            a22 = fmaf(av.z, wv4.z, a22); a23 = fmaf(av.z, wv4.w, a23);
            a30 = fmaf(av.w, wv4.x, a30); a31 = fmaf(av.w, wv4.y, a31);
            a32 = fmaf(av.w, wv4.z, a32); a33 = fmaf(av.w, wv4.w, a33);
        }
        *(float4*)&sH2[(4 * eg + 0) * 68 + j4] =
            make_float4(silu(a00), silu(a01), silu(a02), silu(a03));
        *(float4*)&sH2[(4 * eg + 1) * 68 + j4] =
            make_float4(silu(a10), silu(a11), silu(a12), silu(a13));
        *(float4*)&sH2[(4 * eg + 2) * 68 + j4] =
            make_float4(silu(a20), silu(a21), silu(a22), silu(a23));
        *(float4*)&sH2[(4 * eg + 3) * 68 + j4] =
            make_float4(silu(a30), silu(a31), silu(a32), silu(a33));
    }
    __syncthreads();  // sH2 ready; sH1T dead -> union free for sTP

    // ---- P3: barrier-free GEMM
    // acc[i][j] = sum_k sH2[i*8+eb][k] * W3[k][cb8+j]; W3 via VMEM (L2-hot)
    float acc[8][8];
#pragma unroll
    for (int i = 0; i < 8; ++i)
#pragma unroll
        for (int j = 0; j < 8; ++j) acc[i][j] = 0.f;

#pragma unroll 1
    for (int kt = 0; kt < 16; ++kt) {  // K-step 4
        float4 h[8];
#pragma unroll
        for (int i = 0; i < 8; ++i)
            h[i] = *(const float4*)&sH2[(i * 8 + eb) * 68 + kt * 4];
#pragma unroll
        for (int kk = 0; kk < 4; ++kk) {
            const int k = kt * 4 + kk;
            float4 wa = *(const float4*)&W3[k * 320 + cb8];
            float4 wb = *(const float4*)&W3[k * 320 + cb8 + 4];
#pragma unroll
            for (int i = 0; i < 8; ++i) {
                float hv = (kk == 0) ? h[i].x
                         : (kk == 1) ? h[i].y
                         : (kk == 2) ? h[i].z
                                     : h[i].w;
                acc[i][0] = fmaf(hv, wa.x, acc[i][0]);
                acc[i][1] = fmaf(hv, wa.y, acc[i][1]);
                acc[i][2] = fmaf(hv, wa.z, acc[i][2]);
                acc[i][3] = fmaf(hv, wa.w, acc[i][3]);
                acc[i][4] = fmaf(hv, wb.x, acc[i][4]);
                acc[i][5] = fmaf(hv, wb.y, acc[i][5]);
                acc[i][6] = fmaf(hv, wb.z, acc[i][6]);
                acc[i][7] = fmaf(hv, wb.w, acc[i][7]);
            }
        }
    }

    // ---- P4: 4 message phases, 16 contiguous receiver-sorted edges each.
    // Staging unchanged (all 320 threads, 5 paths). Message loop: thread
    // (q = t>>6, cc = t&63), t<256, walks edges q*4..q*4+3 of the phase,
    // merging same-receiver runs; flush 4 atomics on receiver change only.
#pragma unroll
    for (int g = 0; g < 4; ++g) {
        {
            const int rowA = (wv * 16 + eb) * 68 + c0;
            const int rowB = (wv * 16 + 8 + eb) * 68 + c0;
            *(float4*)&sTP[rowA] =
                make_float4(acc[2 * g][0], acc[2 * g][1], acc[2 * g][2], acc[2 * g][3]);
            *(float4*)&sTP[rowA + 4] =
                make_float4(acc[2 * g][4], acc[2 * g][5], acc[2 * g][6], acc[2 * g][7]);
            *(float4*)&sTP[rowB] =
                make_float4(acc[2 * g + 1][0], acc[2 * g + 1][1], acc[2 * g + 1][2], acc[2 * g + 1][3]);
            *(float4*)&sTP[rowB + 4] =
                make_float4(acc[2 * g + 1][4], acc[2 * g + 1][5], acc[2 * g + 1][6], acc[2 * g + 1][7]);
        }
        __syncthreads();  // tpw staged
        if (t < 256) {
            const int q = t >> 6, cc = t & 63;
            int r_cur = -1;
            float b0 = 0.f, bx = 0.f, by = 0.f, bz = 0.f;
#pragma unroll
            for (int j = 0; j < 4; ++j) {
                int i = q * 4 + j;
                int el = g * 16 + i;
                int s = sSend[el], r = sRecv[el];
                if (r != r_cur) {  // wave-uniform branch (one wave = one q)
                    if (r_cur >= 0) {
                        atomicAdd(&M0[r_cur * 64 + cc], b0);
                        atomicAdd(&M1[r_cur * 192 + cc], bx);
                        atomicAdd(&M1[r_cur * 192 + 64 + cc], by);
                        atomicAdd(&M1[r_cur * 192 + 128 + cc], bz);
                    }
                    r_cur = r;
                    b0 = bx = by = bz = 0.f;
                }
                float X0 = x0[s * 64 + cc];
                float Xx = x1[s * 192 + cc];
                float Xy = x1[s * 192 + 64 + cc];
                float Xz = x1[s * 192 + 128 + cc];
                float Yx = sY1[el][0], Yy = sY1[el][1], Yz = sY1[el][2];
                float t0 = sTP[(0 * 16 + i) * 68 + cc];
                float t1 = sTP[(1 * 16 + i) * 68 + cc];
                float t2 = sTP[(2 * 16 + i) * 68 + cc];
                float t3 = sTP[(3 * 16 + i) * 68 + cc];
                float t4 = sTP[(4 * 16 + i) * 68 + cc];
                float dotp = Xx * Yx + Xy * Yy + Xz * Yz;
                float m0 = t0 * X0 + t3 * (dotp * INV_SQRT3_F);
                float cx = Xy * Yz - Xz * Yy;
                float cy = Xz * Yx - Xx * Yz;
                float cz = Xx * Yy - Xy * Yx;
                float m1x = t1 * X0 * Yx + t2 * Xx + t4 * (cx * INV_SQRT2_F);
                float m1y = t1 * X0 * Yy + t2 * Xy + t4 * (cy * INV_SQRT2_F);
                float m1z = t1 * X0 * Yz + t2 * Xz + t4 * (cz * INV_SQRT2_F);
                b0 = fmaf(m0, INV_AVG_NN, b0);
                bx = fmaf(m1x, INV_AVG_NN, bx);
                by = fmaf(m1y, INV_AVG_NN, by);
                bz = fmaf(m1z, INV_AVG_NN, bz);
            }
            atomicAdd(&M0[r_cur * 64 + cc], b0);
            atomicAdd(&M1[r_cur * 192 + cc], bx);
            atomicAdd(&M1[r_cur * 192 + 64 + cc], by);
            atomicAdd(&M1[r_cur * 192 + 128 + cc], bz);
        }
        __syncthreads();  // sTP reads done before next phase overwrites it
    }
}

// ---------------------------------------------------------------------------
// Fused layer-0 node update + layer-1 lin_up. (unchanged from round 11)
__global__ __launch_bounds__(256) void k_nodelin(
    float* __restrict__ h0, float* __restrict__ h1,
    const int* __restrict__ species,
    const float* __restrict__ linW0, const float* __restrict__ linW1,
    const float* __restrict__ prodW0, const float* __restrict__ prodW1,
    const float* __restrict__ plinW0, const float* __restrict__ plinW1,
    const float* __restrict__ lupW0, const float* __restrict__ lupW1,
    float* __restrict__ x0, float* __restrict__ x1, int nnodes) {
    __shared__ float sh[4][4][64];
    const int w = threadIdx.x >> 6, k = threadIdx.x & 63;
    const int n = blockIdx.x * 4 + w;
    const bool valid = n < nnodes;
    float v0 = valid ? h0[n * 64 + k] : 0.f;
    float v1 = valid ? h1[n * 192 + k] : 0.f;
    float v2 = valid ? h1[n * 192 + 64 + k] : 0.f;
    float v3 = valid ? h1[n * 192 + 128 + k] : 0.f;
    sh[w][0][k] = v0; sh[w][1][k] = v1; sh[w][2][k] = v2; sh[w][3][k] = v3;
    if (valid) {  // zero scatter accumulators for layer 1
        h0[n * 64 + k] = 0.f;
        h1[n * 192 + k] = 0.f;
        h1[n * 192 + 64 + k] = 0.f;
        h1[n * 192 + 128 + k] = 0.f;
    }
    __syncthreads();
    float a0 = 0.f, a1 = 0.f, a2 = 0.f, a3 = 0.f;
    for (int c = 0; c < 64; ++c) {
        float w0 = linW0[c * 64 + k], w1 = linW1[c * 64 + k];
        a0 = fmaf(sh[w][0][c], w0, a0);
        a1 = fmaf(sh[w][1][c], w1, a1);
        a2 = fmaf(sh[w][2][c], w1, a2);
        a3 = fmaf(sh[w][3][c], w1, a3);
    }
    int sp = valid ? species[n] : 0;
    float p00 = prodW0[sp * 192 + k];
    float p01 = prodW0[sp * 192 + 64 + k];
    float p02 = prodW0[sp * 192 + 128 + k];
    float p10 = prodW1[sp * 128 + k];
    float p11 = prodW1[sp * 128 + 64 + k];
    float nsq = a1 * a1 + a2 * a2 + a3 * a3;
    float b0 = p00 * a0 + p01 * (a0 * a0) + p02 * (nsq * INV_SQRT3_F);
    float b1x = p10 * a1 + p11 * (a0 * a1);
    float b1y = p10 * a2 + p11 * (a0 * a2);
    float b1z = p10 * a3 + p11 * (a0 * a3);
    __syncthreads();
    sh[w][0][k] = b0; sh[w][1][k] = b1x; sh[w][2][k] = b1y; sh[w][3][k] = b1z;
    __syncthreads();
    a0 = a1 = a2 = a3 = 0.f;
    for (int c = 0; c < 64; ++c) {
        float w0 = plinW0[c * 64 + k], w1 = plinW1[c * 64 + k];
        a0 = fmaf(sh[w][0][c], w0, a0);
        a1 = fmaf(sh[w][1][c], w1, a1);
        a2 = fmaf(sh[w][2][c], w1, a2);
        a3 = fmaf(sh[w][3][c], w1, a3);
    }
    __syncthreads();
    sh[w][0][k] = a0; sh[w][1][k] = a1; sh[w][2][k] = a2; sh[w][3][k] = a3;
    __syncthreads();
    a0 = a1 = a2 = a3 = 0.f;
    for (int c = 0; c < 64; ++c) {
        float w0 = lupW0[c * 64 + k], w1 = lupW1[c * 64 + k];
        a0 = fmaf(sh[w][0][c], w0, a0);
        a1 = fmaf(sh[w][1][c], w1, a1);
        a2 = fmaf(sh[w][2][c], w1, a2);
        a3 = fmaf(sh[w][3][c], w1, a3);
    }
    if (valid) {
        x0[n * 64 + k] = a0;
        x1[n * 192 + k] = a1;
        x1[n * 192 + 64 + k] = a2;
        x1[n * 192 + 128 + k] = a3;
    }
}

// ---------------------------------------------------------------------------
// Fused layer-1 node update + output write. (unchanged from round 11)
__global__ __launch_bounds__(256) void k_nodeout(
    const float* __restrict__ h0, const float* __restrict__ h1,
    const int* __restrict__ species,
    const float* __restrict__ linW0, const float* __restrict__ linW1,
    const float* __restrict__ prodW0, const float* __restrict__ prodW1,
    const float* __restrict__ plinW0, const float* __restrict__ plinW1,
    float4* __restrict__ out, int nnodes) {
    __shared__ float sh[4][4][64];
    const int w = threadIdx.x >> 6, k = threadIdx.x & 63;
    const int n = blockIdx.x * 4 + w;
    const bool valid = n < nnodes;
    float v0 = valid ? h0[n * 64 + k] : 0.f;
    float v1 = valid ? h1[n * 192 + k] : 0.f;
    float v2 = valid ? h1[n * 192 + 64 + k] : 0.f;
    float v3 = valid ? h1[n * 192 + 128 + k] : 0.f;
    sh[w][0][k] = v0; sh[w][1][k] = v1; sh[w][2][k] = v2; sh[w][3][k] = v3;
    __syncthreads();
    float a0 = 0.f, a1 = 0.f, a2 = 0.f, a3 = 0.f;
    for (int c = 0; c < 64; ++c) {
        float w0 = linW0[c * 64 + k], w1 = linW1[c * 64 + k];
        a0 = fmaf(sh[w][0][c], w0, a0);
        a1 = fmaf(sh[w][1][c], w1, a1);
        a2 = fmaf(sh[w][2][c], w1, a2);
        a3 = fmaf(sh[w][3][c], w1, a3);
    }
    int sp = valid ? species[n] : 0;
    float p00 = prodW0[sp * 192 + k];
    float p01 = prodW0[sp * 192 + 64 + k];
    float p02 = prodW0[sp * 192 + 128 + k];
    float p10 = prodW1[sp * 128 + k];
    float p11 = prodW1[sp * 128 + 64 + k];
    float nsq = a1 * a1 + a2 * a2 + a3 * a3;
    float b0 = p00 * a0 + p01 * (a0 * a0) + p02 * (nsq * INV_SQRT3_F);
    float b1x = p10 * a1 + p11 * (a0 * a1);
    float b1y = p10 * a2 + p11 * (a0 * a2);
    float b1z = p10 * a3 + p11 * (a0 * a3);
    __syncthreads();
    sh[w][0][k] = b0; sh[w][1][k] = b1x; sh[w][2][k] = b1y; sh[w][3][k] = b1z;
    __syncthreads();
    a0 = a1 = a2 = a3 = 0.f;
    for (int c = 0; c < 64; ++c) {
        float w0 = plinW0[c * 64 + k], w1 = plinW1[c * 64 + k];
        a0 = fmaf(sh[w][0][c], w0, a0);
        a1 = fmaf(sh[w][1][c], w1, a1);
        a2 = fmaf(sh[w][2][c], w1, a2);
        a3 = fmaf(sh[w][3][c], w1, a3);
    }
    if (valid) out[n * 64 + k] = make_float4(a0, a1, a2, a3);
}

// ---------------------------------------------------------------------------
extern "C" void kernel_launch(void* const* d_in, const int* in_sizes, int n_in,
                              void* d_out, int out_size, void* d_ws,
                              size_t ws_size, hipStream_t stream) {
    const float* positions = (const float*)d_in[0];
    const int* species = (const int*)d_in[1];
    const int* eidx = (const int*)d_in[2];
    const float* embedW = (const float*)d_in[3];
    const float* linupW0 = (const float*)d_in[4];
    const float* linupW1 = (const float*)d_in[5];
    const float* mlpW1 = (const float*)d_in[6];
    const float* mlpW2 = (const float*)d_in[7];
    const float* mlpW3 = (const float*)d_in[8];
    const float* linW0 = (const float*)d_in[9];
    const float* linW1 = (const float*)d_in[10];
    const float* prodW0 = (const float*)d_in[11];
    const float* prodW1 = (const float*)d_in[12];
    const float* plinW0 = (const float*)d_in[13];
    const float* plinW1 = (const float*)d_in[14];

    const int nn = in_sizes[0] / 3;   // 25000
    const int ne = in_sizes[2] / 2;   // 400000

    // workspace layout (floats): h0 | h1 | x0 | x1 | eidx2(int)
    float* h0 = (float*)d_ws;
    float* h1 = h0 + (size_t)nn * 64;
    float* x0 = h1 + (size_t)nn * 192;
    float* x1 = x0 + (size_t)nn * 64;
    int* eidx2 = (int*)(x1 + (size_t)nn * 192);

    const int gridNode = (nn + 3) / 4;
    const int gridEdge = (ne + 63) / 64;
    const int gridE256 = (ne + 255) / 256;

    // ---- receiver-sort the edge list (both edge kernels merge atomics).
    // cnt aliases x1 (dead until k_nodelin). Guard on workspace capacity;
    // fall back to unsorted edges (merge still correct, just fewer merges).
    const size_t needed =
        ((size_t)nn * 512) * sizeof(float) + (size_t)2 * ne * sizeof(int);
    const int* eidx_use = eidx;
    if (ws_size >= needed) {
        int* cnt = (int*)x1;
        hipMemsetAsync(cnt, 0, (size_t)nn * sizeof(int), stream);
        k_hist<<<gridE256, 256, 0, stream>>>(eidx, cnt, ne);
        k_scan<<<1, 1024, 0, stream>>>(cnt, nn);
        k_scatter<<<gridE256, 256, 0, stream>>>(eidx, cnt, eidx2, ne);
        eidx_use = eidx2;
    }

    // ---- layer 0 (merged atomics, receiver-sorted edges)
    k_lin0<<<gridNode, 256, 0, stream>>>(
        h0, h1, species, embedW, linupW0, x0, nn);
    k_edge0<<<gridEdge, 320, 0, stream>>>(
        positions, eidx_use, x0, mlpW1, mlpW2, mlpW3, h0, h1, ne);

    // ---- layer-0 node update fused with layer-1 lin_up
    k_nodelin<<<gridNode, 256, 0, stream>>>(
        h0, h1, species, linW0, linW1, prodW0, prodW1, plinW0, plinW1,
        linupW0 + 4096, linupW1 + 4096, x0, x1, nn);

    // ---- layer 1 (merged atomics, receiver-sorted edges)
    k_edge1<<<gridEdge, 320, 0, stream>>>(
        positions, eidx_use, x0, x1, mlpW1 + 512, mlpW2 + 4096,
        mlpW3 + 20480, h0, h1, ne);

    // ---- layer-1 node update fused with output write
    k_nodeout<<<gridNode, 256, 0, stream>>>(
        h0, h1, species, linW0 + 4096, linW1 + 4096,
        prodW0 + 768, prodW1 + 512, plinW0 + 4096, plinW1 + 4096,
        (float4*)d_out, nn);
}